// Round 1
// baseline (681.887 us; speedup 1.0000x reference)
//
#include <hip/hip_runtime.h>
#include <cstddef>

// Shapes: BS=16, N=1024, HID=64, D=128, F=128, C=256, NM=4, PREK=4
constexpr float PHASE_SCALE = (float)(3.141592653589793 / ((12.0 + 2.0) / 64.0));

// ---------------- build x0 = concat([re_in, re_p, im_in, im_p]) ----------------
__global__ __launch_bounds__(256) void build_x0_kernel(
    const float* __restrict__ inp, const float* __restrict__ hs, float* __restrict__ x0)
{
    int gi = blockIdx.x * 256 + threadIdx.x;      // 16*1024*256
    int c = gi & 255;
    int n = (gi >> 8) & 1023;
    int b = gi >> 18;
    const float* irow = inp + ((size_t)b * 1024 + n) * 128;
    const float* prow = hs + (((size_t)b * 4 + 3) * 1024 + n) * 128;  // hidden[:, -1]
    float v;
    if (c < 64)       v = irow[c];
    else if (c < 128) v = prow[c - 64];
    else if (c < 192) v = irow[c - 64];
    else              v = prow[c - 128];
    x0[gi] = v;
}

// -------- rearrange gc_w (128 x 1024) -> gt[m][c][d] = gc_w[d][c*4+m] --------
__global__ __launch_bounds__(256) void rearrange_gcw_kernel(
    const float* __restrict__ gcw, float* __restrict__ gt)
{
    int gi = blockIdx.x * 256 + threadIdx.x;      // 4*256*128 = 131072
    int m = gi >> 15;
    int rem = gi & 32767;
    int c = rem >> 7;
    int d = rem & 127;
    gt[gi] = gcw[(size_t)d * 1024 + c * 4 + m];
}

// -------- new_hidden[:, :3] = hidden_states[:, 1:] (float4 copy) --------
__global__ __launch_bounds__(256) void copy_hidden_kernel(
    const float4* __restrict__ src, float4* __restrict__ dst)
{
    int gi = blockIdx.x * 256 + threadIdx.x;      // 16*3*131072/4 = 1572864
    int b = gi / 98304;
    int off = gi - b * 98304;
    dst[(size_t)b * 131072 + off] = src[(size_t)b * 131072 + 32768 + off];
}

// -------- attention partial sums: sa[b,k] pieces over n-chunks --------
__global__ __launch_bounds__(256) void att_partial_kernel(
    const float* __restrict__ hs, const float* __restrict__ R,
    const float* __restrict__ attw, float* __restrict__ part)
{
    int bk = blockIdx.x;            // 0..63  (b*4+k)
    int k = bk & 3;
    int chunk = blockIdx.y;         // 0..7 -> n in [chunk*128, chunk*128+128)
    const float* hbase = hs + (size_t)bk * 1024 * 128;
    float acc = 0.f;
    for (int idx = threadIdx.x; idx < 128 * 64; idx += 256) {
        int h = idx & 63;
        int n = chunk * 128 + (idx >> 6);
        float ph = R[(size_t)k * 65536 + n * 64 + h] * PHASE_SCALE;
        float s, c;
        sincosf(ph, &s, &c);
        float re = hbase[(size_t)n * 128 + h];
        float im = hbase[(size_t)n * 128 + 64 + h];
        float rn = c * re - s * im;
        float in_ = s * re + c * im;
        acc += rn * attw[n * 128 + h] + in_ * attw[n * 128 + 64 + h];
    }
    __shared__ float red[256];
    red[threadIdx.x] = acc;
    __syncthreads();
    for (int s2 = 128; s2 > 0; s2 >>= 1) {
        if (threadIdx.x < (unsigned)s2) red[threadIdx.x] += red[threadIdx.x + s2];
        __syncthreads();
    }
    if (threadIdx.x == 0) part[bk * 8 + chunk] = red[0];
}

// -------- softmax over k (size 4) --------
__global__ __launch_bounds__(64) void att_softmax_kernel(
    const float* __restrict__ part, const float* __restrict__ attb, float* __restrict__ wa)
{
    int b = threadIdx.x;
    if (b >= 16) return;
    float sa[4];
    float mx = -1e30f;
    for (int k = 0; k < 4; ++k) {
        float s = attb[0];
        for (int c = 0; c < 8; ++c) s += part[(b * 4 + k) * 8 + c];
        sa[k] = s;
        mx = fmaxf(mx, s);
    }
    float den = 0.f;
    for (int k = 0; k < 4; ++k) { sa[k] = expf(sa[k] - mx); den += sa[k]; }
    for (int k = 0; k < 4; ++k) wa[b * 4 + k] = sa[k] / den;
}

// -------- att[b,n,d] = sum_k wa[b,k] * rot(hidden)[b,k,n,d] --------
__global__ __launch_bounds__(256) void att_compute_kernel(
    const float* __restrict__ hs, const float* __restrict__ R,
    const float* __restrict__ wa, float* __restrict__ att)
{
    int gi = blockIdx.x * 256 + threadIdx.x;      // 16*1024*128
    int d = gi & 127;
    int n = (gi >> 7) & 1023;
    int b = gi >> 17;
    int h = d & 63;
    bool isre = (d < 64);
    float acc = 0.f;
    #pragma unroll
    for (int k = 0; k < 4; ++k) {
        float ph = R[(size_t)k * 65536 + n * 64 + h] * PHASE_SCALE;
        float s, c;
        sincosf(ph, &s, &c);
        const float* hb = hs + ((((size_t)b * 4 + k) * 1024 + n) * 128);
        float re = hb[h];
        float im = hb[64 + h];
        float v = isre ? (c * re - s * im) : (s * re + c * im);
        acc += wa[b * 4 + k] * v;
    }
    att[gi] = acc;
}

// -------- Chebyshev GEMM: xnext = alpha * (S @ xcur) - (xprev?) --------
// per batch: M=1024, K=1024, Ncols=256; BM=BN=64, BK=16
__global__ __launch_bounds__(256) void cheb_gemm_kernel(
    const float* __restrict__ S, const float* __restrict__ xcur,
    const float* __restrict__ xprev, float* __restrict__ xnext, float alpha)
{
    const int b = blockIdx.z;
    const int n0 = blockIdx.x * 64;
    const int m0 = blockIdx.y * 64;
    const float* A = S + (size_t)b * 1024 * 1024;
    const float* Bm = xcur + (size_t)b * 1024 * 256;

    __shared__ float As[64][17];
    __shared__ float Bs[16][64];

    const int tid = threadIdx.x;
    const int tr = tid >> 4, tc = tid & 15;
    const int a_row = tid >> 2, a_col = (tid & 3) * 4;
    const int b_row = tid >> 4, b_col = (tid & 15) * 4;

    float acc[4][4] = {};

    for (int k0 = 0; k0 < 1024; k0 += 16) {
        float4 av = *(const float4*)(A + (size_t)(m0 + a_row) * 1024 + k0 + a_col);
        float4 bv = *(const float4*)(Bm + (size_t)(k0 + b_row) * 256 + n0 + b_col);
        As[a_row][a_col + 0] = av.x;
        As[a_row][a_col + 1] = av.y;
        As[a_row][a_col + 2] = av.z;
        As[a_row][a_col + 3] = av.w;
        *(float4*)&Bs[b_row][b_col] = bv;
        __syncthreads();
        #pragma unroll
        for (int k = 0; k < 16; ++k) {
            float ar[4], br[4];
            #pragma unroll
            for (int i = 0; i < 4; ++i) ar[i] = As[tr * 4 + i][k];
            #pragma unroll
            for (int j = 0; j < 4; ++j) br[j] = Bs[k][tc * 4 + j];
            #pragma unroll
            for (int i = 0; i < 4; ++i)
                #pragma unroll
                for (int j = 0; j < 4; ++j)
                    acc[i][j] = fmaf(ar[i], br[j], acc[i][j]);
        }
        __syncthreads();
    }

    float* Cm = xnext + (size_t)b * 1024 * 256;
    const float* Pm = xprev ? (xprev + (size_t)b * 1024 * 256) : nullptr;
    #pragma unroll
    for (int i = 0; i < 4; ++i) {
        int r = m0 + tr * 4 + i;
        size_t base = (size_t)r * 256 + n0 + tc * 4;
        float4 o;
        o.x = alpha * acc[i][0];
        o.y = alpha * acc[i][1];
        o.z = alpha * acc[i][2];
        o.w = alpha * acc[i][3];
        if (Pm) {
            float4 p = *(const float4*)(Pm + base);
            o.x -= p.x; o.y -= p.y; o.z -= p.z; o.w -= p.w;
        }
        *(float4*)(Cm + base) = o;
    }
}

// -------- gco GEMM: gco (+)= xs @ gt_m   (M=16384, K=256, N=128) --------
__global__ __launch_bounds__(256) void gco_gemm_kernel(
    const float* __restrict__ A, const float* __restrict__ Bm,
    const float* __restrict__ bias, float* __restrict__ Cmat, int mode)
{
    const int n0 = blockIdx.x * 64;
    const int m0 = blockIdx.y * 64;
    __shared__ float As[64][17];
    __shared__ float Bs[16][64];
    const int tid = threadIdx.x;
    const int tr = tid >> 4, tc = tid & 15;
    const int a_row = tid >> 2, a_col = (tid & 3) * 4;
    const int b_row = tid >> 4, b_col = (tid & 15) * 4;
    float acc[4][4] = {};
    for (int k0 = 0; k0 < 256; k0 += 16) {
        float4 av = *(const float4*)(A + (size_t)(m0 + a_row) * 256 + k0 + a_col);
        float4 bv = *(const float4*)(Bm + (size_t)(k0 + b_row) * 128 + n0 + b_col);
        As[a_row][a_col + 0] = av.x;
        As[a_row][a_col + 1] = av.y;
        As[a_row][a_col + 2] = av.z;
        As[a_row][a_col + 3] = av.w;
        *(float4*)&Bs[b_row][b_col] = bv;
        __syncthreads();
        #pragma unroll
        for (int k = 0; k < 16; ++k) {
            float ar[4], br[4];
            #pragma unroll
            for (int i = 0; i < 4; ++i) ar[i] = As[tr * 4 + i][k];
            #pragma unroll
            for (int j = 0; j < 4; ++j) br[j] = Bs[k][tc * 4 + j];
            #pragma unroll
            for (int i = 0; i < 4; ++i)
                #pragma unroll
                for (int j = 0; j < 4; ++j)
                    acc[i][j] = fmaf(ar[i], br[j], acc[i][j]);
        }
        __syncthreads();
    }
    #pragma unroll
    for (int i = 0; i < 4; ++i) {
        int r = m0 + tr * 4 + i;
        size_t base = (size_t)r * 128 + n0 + tc * 4;
        float4 o = {acc[i][0], acc[i][1], acc[i][2], acc[i][3]};
        if (mode == 0) {
            o.x += bias[n0 + tc * 4 + 0];
            o.y += bias[n0 + tc * 4 + 1];
            o.z += bias[n0 + tc * 4 + 2];
            o.w += bias[n0 + tc * 4 + 3];
        } else {
            float4 p = *(const float4*)(Cmat + base);
            o.x += p.x; o.y += p.y; o.z += p.z; o.w += p.w;
        }
        *(float4*)(Cmat + base) = o;
    }
}

// -------- final: out = leaky(gco) @ W + b + att ; also writes new_hidden[:,3] --------
__global__ __launch_bounds__(256) void final_gemm_kernel(
    const float* __restrict__ gco, const float* __restrict__ W,
    const float* __restrict__ bvec, const float* __restrict__ att,
    float* __restrict__ out, float* __restrict__ newh)
{
    const int n0 = blockIdx.x * 64;
    const int m0 = blockIdx.y * 64;
    __shared__ float As[64][17];
    __shared__ float Bs[16][64];
    const int tid = threadIdx.x;
    const int tr = tid >> 4, tc = tid & 15;
    const int a_row = tid >> 2, a_col = (tid & 3) * 4;
    const int b_row = tid >> 4, b_col = (tid & 15) * 4;
    float acc[4][4] = {};
    for (int k0 = 0; k0 < 128; k0 += 16) {
        float4 av = *(const float4*)(gco + (size_t)(m0 + a_row) * 128 + k0 + a_col);
        float4 bv = *(const float4*)(W + (size_t)(k0 + b_row) * 128 + n0 + b_col);
        // leaky relu on A (conv_out = leaky(gco))
        As[a_row][a_col + 0] = av.x >= 0.f ? av.x : 0.01f * av.x;
        As[a_row][a_col + 1] = av.y >= 0.f ? av.y : 0.01f * av.y;
        As[a_row][a_col + 2] = av.z >= 0.f ? av.z : 0.01f * av.z;
        As[a_row][a_col + 3] = av.w >= 0.f ? av.w : 0.01f * av.w;
        *(float4*)&Bs[b_row][b_col] = bv;
        __syncthreads();
        #pragma unroll
        for (int k = 0; k < 16; ++k) {
            float ar[4], br[4];
            #pragma unroll
            for (int i = 0; i < 4; ++i) ar[i] = As[tr * 4 + i][k];
            #pragma unroll
            for (int j = 0; j < 4; ++j) br[j] = Bs[k][tc * 4 + j];
            #pragma unroll
            for (int i = 0; i < 4; ++i)
                #pragma unroll
                for (int j = 0; j < 4; ++j)
                    acc[i][j] = fmaf(ar[i], br[j], acc[i][j]);
        }
        __syncthreads();
    }
    #pragma unroll
    for (int i = 0; i < 4; ++i) {
        int r = m0 + tr * 4 + i;
        int bidx = r >> 10;
        int n = r & 1023;
        int col = n0 + tc * 4;
        size_t base = (size_t)r * 128 + col;
        float4 bb = *(const float4*)(bvec + (size_t)n * 128 + col);
        float4 aa = *(const float4*)(att + base);
        float4 o;
        o.x = acc[i][0] + bb.x + aa.x;
        o.y = acc[i][1] + bb.y + aa.y;
        o.z = acc[i][2] + bb.z + aa.z;
        o.w = acc[i][3] + bb.w + aa.w;
        *(float4*)(out + base) = o;
        *(float4*)(newh + (size_t)bidx * 524288 + 393216 + (size_t)n * 128 + col) = o;
    }
}

extern "C" void kernel_launch(void* const* d_in, const int* in_sizes, int n_in,
                              void* d_out, int out_size, void* d_ws, size_t ws_size,
                              hipStream_t stream) {
    const float* inp  = (const float*)d_in[0];
    const float* sup  = (const float*)d_in[1];
    const float* hs   = (const float*)d_in[2];
    const float* W    = (const float*)d_in[3];
    const float* bvec = (const float*)d_in[4];
    const float* R    = (const float*)d_in[5];
    const float* gcw  = (const float*)d_in[6];
    const float* gcb  = (const float*)d_in[7];
    // d_in[8], d_in[9] (ev_att_w/b) are dead: softmax over a size-1 axis == 1
    const float* attw = (const float*)d_in[10];
    const float* attb = (const float*)d_in[11];

    float* out  = (float*)d_out;                    // (16,1024,128)
    float* newh = out + 2097152;                    // (16,4,1024,128)

    float* wsf  = (float*)d_ws;
    float* xA   = wsf;                              // 4,194,304 floats
    float* xB   = xA + 4194304;
    float* xC   = xB + 4194304;
    float* gt   = xC + 4194304;                     // 131072
    float* gco  = gt + 131072;                      // 2,097,152
    float* attb_buf = gco + 2097152;                // 2,097,152
    float* part = attb_buf + 2097152;               // 512
    float* wa   = part + 512;                       // 64
    // total ~16.9M floats (~67.6 MB)

    build_x0_kernel<<<16384, 256, 0, stream>>>(inp, hs, xA);
    rearrange_gcw_kernel<<<512, 256, 0, stream>>>(gcw, gt);
    copy_hidden_kernel<<<6144, 256, 0, stream>>>((const float4*)hs, (float4*)newh);
    att_partial_kernel<<<dim3(64, 8), 256, 0, stream>>>(hs, R, attw, part);
    att_softmax_kernel<<<1, 64, 0, stream>>>(part, attb, wa);
    att_compute_kernel<<<8192, 256, 0, stream>>>(hs, R, wa, attb_buf);

    // gco = x0 @ g0 + gc_b ; x1 = S@x0 ; gco += x1@g1 ; x2 = 2S@x1 - x0 ; ...
    gco_gemm_kernel<<<dim3(2, 256), 256, 0, stream>>>(xA, gt + 0 * 32768, gcb, gco, 0);
    cheb_gemm_kernel<<<dim3(4, 16, 16), 256, 0, stream>>>(sup, xA, nullptr, xB, 1.0f);
    gco_gemm_kernel<<<dim3(2, 256), 256, 0, stream>>>(xB, gt + 1 * 32768, gcb, gco, 1);
    cheb_gemm_kernel<<<dim3(4, 16, 16), 256, 0, stream>>>(sup, xB, xA, xC, 2.0f);
    gco_gemm_kernel<<<dim3(2, 256), 256, 0, stream>>>(xC, gt + 2 * 32768, gcb, gco, 2);
    cheb_gemm_kernel<<<dim3(4, 16, 16), 256, 0, stream>>>(sup, xC, xB, xA, 2.0f);
    gco_gemm_kernel<<<dim3(2, 256), 256, 0, stream>>>(xA, gt + 3 * 32768, gcb, gco, 3);

    final_gemm_kernel<<<dim3(2, 256), 256, 0, stream>>>(gco, W, bvec, attb_buf, out, newh);
}

// Round 2
// 452.006 us; speedup vs baseline: 1.5086x; 1.5086x over previous
//
#include <hip/hip_runtime.h>
#include <cstddef>

// Shapes: BS=16, N=1024, HID=64, D=128, F=128, C=256, NM=4, PREK=4
constexpr float PHASE_SCALE = (float)(3.141592653589793 / ((12.0 + 2.0) / 64.0));

typedef __bf16 bf16;
typedef __bf16 bf16x4 __attribute__((ext_vector_type(4)));
typedef __bf16 bf16x8 __attribute__((ext_vector_type(8)));
typedef float floatx4 __attribute__((ext_vector_type(4)));

// ---------------- S fp32 -> bf16 (written into the newh region of d_out) ----------------
__global__ __launch_bounds__(256) void s_convert_kernel(
    const float4* __restrict__ S, bf16* __restrict__ Sbf)
{
    int gi = blockIdx.x * 256 + threadIdx.x;   // 4,194,304 threads (16M floats / 4)
    float4 v = S[gi];
    bf16x4 o;
    o[0] = (bf16)v.x; o[1] = (bf16)v.y; o[2] = (bf16)v.z; o[3] = (bf16)v.w;
    *(bf16x4*)(Sbf + (size_t)gi * 4) = o;
}

// ---------------- weight prep: gtT[m][d][c] = gc_w[d][c*4+m]; WT[n][k] = W[k][n] ----------------
__global__ __launch_bounds__(256) void prep_weights_kernel(
    const float* __restrict__ gcw, const float* __restrict__ W,
    bf16* __restrict__ gtT, bf16* __restrict__ WT)
{
    int gi = blockIdx.x * 256 + threadIdx.x;   // 131072 + 16384 = 147456
    if (gi < 131072) {
        int m = gi >> 15;
        int rem = gi & 32767;
        int d = rem >> 8;
        int c = rem & 255;
        gtT[gi] = (bf16)gcw[(size_t)d * 1024 + c * 4 + m];
    } else if (gi < 147456) {
        int r = gi - 131072;
        int n = r >> 7, k = r & 127;
        WT[r] = (bf16)W[(size_t)k * 128 + n];
    }
}

// ---------------- rotation tables: cos/sin(R * scale), [4][1024][64] ----------------
__global__ __launch_bounds__(256) void rot_table_kernel(
    const float* __restrict__ R, float* __restrict__ cosT, float* __restrict__ sinT)
{
    int gi = blockIdx.x * 256 + threadIdx.x;   // 262144
    float ph = R[gi] * PHASE_SCALE;
    float s, c;
    sincosf(ph, &s, &c);
    cosT[gi] = c;
    sinT[gi] = s;
}

// ---------------- build x0 (bf16 row-major + transposed) via LDS transpose ----------------
__global__ __launch_bounds__(256) void build_x0_kernel(
    const float* __restrict__ inp, const float* __restrict__ hs,
    bf16* __restrict__ xRow, bf16* __restrict__ xT0)
{
    __shared__ bf16 tile[64][65];
    const int b = blockIdx.z, n0 = blockIdx.y * 64, c0 = blockIdx.x * 64;
    const int tid = threadIdx.x;
    #pragma unroll
    for (int it = 0; it < 16; ++it) {
        int idx = it * 256 + tid;
        int cl = idx & 63, nl = idx >> 6;
        int n = n0 + nl, c = c0 + cl;
        const float* irow = inp + ((size_t)b * 1024 + n) * 128;
        const float* prow = hs + (((size_t)b * 4 + 3) * 1024 + n) * 128;
        float v;
        if (c < 64)       v = irow[c];
        else if (c < 128) v = prow[c - 64];
        else if (c < 192) v = irow[c - 64];
        else              v = prow[c - 128];
        bf16 vb = (bf16)v;
        xRow[((size_t)b * 1024 + n) * 256 + c] = vb;
        tile[nl][cl] = vb;
    }
    __syncthreads();
    #pragma unroll
    for (int it = 0; it < 16; ++it) {
        int idx = it * 256 + tid;
        int nl = idx & 63, cl = idx >> 6;
        xT0[((size_t)b * 256 + c0 + cl) * 1024 + n0 + nl] = tile[nl][cl];
    }
}

// -------- new_hidden[:, :3] = hidden_states[:, 1:] (float4 copy) --------
__global__ __launch_bounds__(256) void copy_hidden_kernel(
    const float4* __restrict__ src, float4* __restrict__ dst)
{
    int gi = blockIdx.x * 256 + threadIdx.x;      // 1,572,864
    int b = gi / 98304;
    int off = gi - b * 98304;
    dst[(size_t)b * 131072 + off] = src[(size_t)b * 131072 + 32768 + off];
}

// -------- attention partial sums over n-chunks (uses rot tables) --------
__global__ __launch_bounds__(256) void att_partial_kernel(
    const float* __restrict__ hs, const float* __restrict__ cosT,
    const float* __restrict__ sinT, const float* __restrict__ attw,
    float* __restrict__ part)
{
    int bk = blockIdx.x;            // b*4+k
    int k = bk & 3;
    int chunk = blockIdx.y;         // 0..7
    const float* hbase = hs + (size_t)bk * 1024 * 128;
    float acc = 0.f;
    for (int idx = threadIdx.x; idx < 128 * 64; idx += 256) {
        int h = idx & 63;
        int n = chunk * 128 + (idx >> 6);
        float c = cosT[(size_t)k * 65536 + n * 64 + h];
        float s = sinT[(size_t)k * 65536 + n * 64 + h];
        float re = hbase[(size_t)n * 128 + h];
        float im = hbase[(size_t)n * 128 + 64 + h];
        float rn = c * re - s * im;
        float in_ = s * re + c * im;
        acc += rn * attw[n * 128 + h] + in_ * attw[n * 128 + 64 + h];
    }
    __shared__ float red[256];
    red[threadIdx.x] = acc;
    __syncthreads();
    for (int s2 = 128; s2 > 0; s2 >>= 1) {
        if (threadIdx.x < (unsigned)s2) red[threadIdx.x] += red[threadIdx.x + s2];
        __syncthreads();
    }
    if (threadIdx.x == 0) part[bk * 8 + chunk] = red[0];
}

__global__ __launch_bounds__(64) void att_softmax_kernel(
    const float* __restrict__ part, const float* __restrict__ attb, float* __restrict__ wa)
{
    int b = threadIdx.x;
    if (b >= 16) return;
    float sa[4];
    float mx = -1e30f;
    for (int k = 0; k < 4; ++k) {
        float s = attb[0];
        for (int c = 0; c < 8; ++c) s += part[(b * 4 + k) * 8 + c];
        sa[k] = s;
        mx = fmaxf(mx, s);
    }
    float den = 0.f;
    for (int k = 0; k < 4; ++k) { sa[k] = expf(sa[k] - mx); den += sa[k]; }
    for (int k = 0; k < 4; ++k) wa[b * 4 + k] = sa[k] / den;
}

__global__ __launch_bounds__(256) void att_compute_kernel(
    const float* __restrict__ hs, const float* __restrict__ cosT,
    const float* __restrict__ sinT, const float* __restrict__ wa,
    float* __restrict__ att)
{
    int gi = blockIdx.x * 256 + threadIdx.x;      // 16*1024*128
    int d = gi & 127;
    int n = (gi >> 7) & 1023;
    int b = gi >> 17;
    int h = d & 63;
    bool isre = (d < 64);
    float acc = 0.f;
    #pragma unroll
    for (int k = 0; k < 4; ++k) {
        float c = cosT[(size_t)k * 65536 + n * 64 + h];
        float s = sinT[(size_t)k * 65536 + n * 64 + h];
        const float* hb = hs + ((((size_t)b * 4 + k) * 1024 + n) * 128);
        float re = hb[h];
        float im = hb[64 + h];
        float v = isre ? (c * re - s * im) : (s * re + c * im);
        acc += wa[b * 4 + k] * v;
    }
    att[gi] = acc;
}

// ---------------- Chebyshev MFMA GEMM: xnext = alpha*(S @ x) - xprev ----------------
// per batch M=1024(rows n), N=256(cols c), K=1024. Tile 128x128, 4 waves 2x2.
// A = S_bf row-major [n][k]; B = xT [c][k] (k-contiguous). No LDS.
__global__ __launch_bounds__(256) void cheb_mfma_kernel(
    const bf16* __restrict__ S, const bf16* __restrict__ xT,
    const bf16* __restrict__ xTprev, bf16* __restrict__ outT,
    bf16* __restrict__ outRow, float alpha)
{
    const int b = blockIdx.z;
    const int c0 = blockIdx.x * 128;
    const int n0 = blockIdx.y * 128;
    const int tid = threadIdx.x;
    const int wave = tid >> 6, lane = tid & 63;
    const int wr = (wave >> 1) * 64, wc = (wave & 1) * 64;
    const int l15 = lane & 15, quad = lane >> 4;

    const bf16* Sb = S + (size_t)b * 1024 * 1024;
    const bf16* xb = xT + (size_t)b * 256 * 1024;

    const bf16* aptr[4];
    const bf16* bptr[4];
    int colIdx[4];
    #pragma unroll
    for (int t = 0; t < 4; ++t) {
        int row = n0 + wr + t * 16 + l15;
        int col = c0 + wc + t * 16 + l15;
        colIdx[t] = col;
        aptr[t] = Sb + (size_t)row * 1024 + quad * 8;
        bptr[t] = xb + (size_t)col * 1024 + quad * 8;
    }

    floatx4 acc[4][4] = {};
    for (int k0 = 0; k0 < 1024; k0 += 32) {
        bf16x8 af[4], bfr[4];
        #pragma unroll
        for (int t = 0; t < 4; ++t) af[t] = *(const bf16x8*)(aptr[t] + k0);
        #pragma unroll
        for (int t = 0; t < 4; ++t) bfr[t] = *(const bf16x8*)(bptr[t] + k0);
        #pragma unroll
        for (int i = 0; i < 4; ++i)
            #pragma unroll
            for (int j = 0; j < 4; ++j)
                acc[i][j] = __builtin_amdgcn_mfma_f32_16x16x32_bf16(af[i], bfr[j], acc[i][j], 0, 0, 0);
    }

    bf16* oT = outT ? outT + (size_t)b * 256 * 1024 : nullptr;
    bf16* oR = outRow + (size_t)b * 1024 * 256;
    const bf16* pT = xTprev ? xTprev + (size_t)b * 256 * 1024 : nullptr;
    #pragma unroll
    for (int i = 0; i < 4; ++i) {
        int rbase = n0 + wr + i * 16 + quad * 4;   // 4 consecutive rows rbase..rbase+3
        #pragma unroll
        for (int j = 0; j < 4; ++j) {
            int col = colIdx[j];
            float v[4];
            #pragma unroll
            for (int r = 0; r < 4; ++r) v[r] = alpha * acc[i][j][r];
            if (pT) {
                const bf16* pp = pT + (size_t)col * 1024 + rbase;
                #pragma unroll
                for (int r = 0; r < 4; ++r) v[r] -= (float)pp[r];
            }
            bf16x4 o;
            #pragma unroll
            for (int r = 0; r < 4; ++r) o[r] = (bf16)v[r];
            if (oT) *(bf16x4*)(oT + (size_t)col * 1024 + rbase) = o;
            #pragma unroll
            for (int r = 0; r < 4; ++r)
                oR[(size_t)(rbase + r) * 256 + col] = o[r];
        }
    }
}

// ---------------- gco MFMA: gco (+)= xRow @ gtT_hop^T ; M=16384,K=256,N=128 ----------------
// mode 0: init with bias; 1,2: accumulate fp32; 3: accumulate + leaky -> bf16
__global__ __launch_bounds__(256) void gco_mfma_kernel(
    const bf16* __restrict__ xRow, const bf16* __restrict__ gtT,
    const float* __restrict__ gcb, float* __restrict__ gcoF,
    bf16* __restrict__ gcoB, int mode)
{
    const int m0 = blockIdx.y * 128;
    const int tid = threadIdx.x;
    const int wave = tid >> 6, lane = tid & 63;
    const int wr = (wave >> 1) * 64, wc = (wave & 1) * 64;
    const int l15 = lane & 15, quad = lane >> 4;

    const bf16* aptr[4];
    const bf16* bptr[4];
    int colIdx[4];
    #pragma unroll
    for (int t = 0; t < 4; ++t) {
        int row = m0 + wr + t * 16 + l15;
        int col = wc + t * 16 + l15;
        colIdx[t] = col;
        aptr[t] = xRow + (size_t)row * 256 + quad * 8;
        bptr[t] = gtT + (size_t)col * 256 + quad * 8;
    }
    floatx4 acc[4][4] = {};
    for (int k0 = 0; k0 < 256; k0 += 32) {
        bf16x8 af[4], bfr[4];
        #pragma unroll
        for (int t = 0; t < 4; ++t) af[t] = *(const bf16x8*)(aptr[t] + k0);
        #pragma unroll
        for (int t = 0; t < 4; ++t) bfr[t] = *(const bf16x8*)(bptr[t] + k0);
        #pragma unroll
        for (int i = 0; i < 4; ++i)
            #pragma unroll
            for (int j = 0; j < 4; ++j)
                acc[i][j] = __builtin_amdgcn_mfma_f32_16x16x32_bf16(af[i], bfr[j], acc[i][j], 0, 0, 0);
    }
    #pragma unroll
    for (int i = 0; i < 4; ++i) {
        int rbase = m0 + wr + i * 16 + quad * 4;
        #pragma unroll
        for (int j = 0; j < 4; ++j) {
            int col = colIdx[j];
            #pragma unroll
            for (int r = 0; r < 4; ++r) {
                size_t idx = (size_t)(rbase + r) * 128 + col;
                float v = acc[i][j][r];
                if (mode == 0) v += gcb[col];
                else           v += gcoF[idx];
                if (mode == 3) {
                    v = v >= 0.f ? v : 0.01f * v;
                    gcoB[idx] = (bf16)v;
                } else {
                    gcoF[idx] = v;
                }
            }
        }
    }
}

// ---------------- final MFMA: out = gcoB @ WT^T + b + att ; writes out + newh[:,3] ----------------
__global__ __launch_bounds__(256) void final_mfma_kernel(
    const bf16* __restrict__ gcoB, const bf16* __restrict__ WT,
    const float* __restrict__ bvec, const float* __restrict__ attB,
    float* __restrict__ out, float* __restrict__ newh)
{
    const int m0 = blockIdx.y * 128;
    const int tid = threadIdx.x;
    const int wave = tid >> 6, lane = tid & 63;
    const int wr = (wave >> 1) * 64, wc = (wave & 1) * 64;
    const int l15 = lane & 15, quad = lane >> 4;

    const bf16* aptr[4];
    const bf16* bptr[4];
    int colIdx[4];
    #pragma unroll
    for (int t = 0; t < 4; ++t) {
        int row = m0 + wr + t * 16 + l15;
        int col = wc + t * 16 + l15;
        colIdx[t] = col;
        aptr[t] = gcoB + (size_t)row * 128 + quad * 8;
        bptr[t] = WT + (size_t)col * 128 + quad * 8;
    }
    floatx4 acc[4][4] = {};
    for (int k0 = 0; k0 < 128; k0 += 32) {
        bf16x8 af[4], bfr[4];
        #pragma unroll
        for (int t = 0; t < 4; ++t) af[t] = *(const bf16x8*)(aptr[t] + k0);
        #pragma unroll
        for (int t = 0; t < 4; ++t) bfr[t] = *(const bf16x8*)(bptr[t] + k0);
        #pragma unroll
        for (int i = 0; i < 4; ++i)
            #pragma unroll
            for (int j = 0; j < 4; ++j)
                acc[i][j] = __builtin_amdgcn_mfma_f32_16x16x32_bf16(af[i], bfr[j], acc[i][j], 0, 0, 0);
    }
    #pragma unroll
    for (int i = 0; i < 4; ++i) {
        int rbase = m0 + wr + i * 16 + quad * 4;
        #pragma unroll
        for (int j = 0; j < 4; ++j) {
            int col = colIdx[j];
            #pragma unroll
            for (int r = 0; r < 4; ++r) {
                int rr = rbase + r;
                int bidx = rr >> 10, n = rr & 1023;
                float o = acc[i][j][r] + bvec[(size_t)n * 128 + col]
                        + attB[(size_t)rr * 128 + col];
                out[(size_t)rr * 128 + col] = o;
                newh[(size_t)bidx * 524288 + 393216 + (size_t)n * 128 + col] = o;
            }
        }
    }
}

extern "C" void kernel_launch(void* const* d_in, const int* in_sizes, int n_in,
                              void* d_out, int out_size, void* d_ws, size_t ws_size,
                              hipStream_t stream) {
    const float* inp  = (const float*)d_in[0];
    const float* sup  = (const float*)d_in[1];
    const float* hs   = (const float*)d_in[2];
    const float* W    = (const float*)d_in[3];
    const float* bvec = (const float*)d_in[4];
    const float* R    = (const float*)d_in[5];
    const float* gcw  = (const float*)d_in[6];
    const float* gcb  = (const float*)d_in[7];
    // d_in[8], d_in[9] (ev_att_w/b) dead: softmax over size-1 axis == 1
    const float* attw = (const float*)d_in[10];
    const float* attb = (const float*)d_in[11];

    float* out  = (float*)d_out;                    // (16,1024,128)
    float* newh = out + 2097152;                    // (16,4,1024,128) = 33.5 MB
    bf16*  Sbf  = (bf16*)newh;                      // S bf16 lives here until copy_hidden

    char* w = (char*)d_ws;
    bf16*  xT0  = (bf16*)(w);                       // 8 MB  [16][256][1024]
    bf16*  xT1  = (bf16*)(w + 8388608);             // 8 MB
    bf16*  xT2  = (bf16*)(w + 16777216);            // 8 MB
    bf16*  xRow = (bf16*)(w + 25165824);            // 8 MB  [16384][256]
    float* gcoF = (float*)(w + 33554432);           // 8 MB  [16384][128]
    bf16*  gcoB = (bf16*)(w + 41943040);            // 4 MB
    bf16*  gtT  = (bf16*)(w + 46137344);            // 256 KB [4][128][256]
    bf16*  WT   = (bf16*)(w + 46399488);            // 32 KB
    float* cosT = (float*)(w + 46432256);           // 1 MB
    float* sinT = (float*)(w + 47480832);           // 1 MB
    float* attB = (float*)(w + 48529408);           // 8 MB
    float* part = (float*)(w + 56918016);           // 2 KB
    float* wa   = (float*)(w + 56920064);           // 64 B
    // total ~56.9 MB

    s_convert_kernel<<<16384, 256, 0, stream>>>((const float4*)sup, Sbf);
    prep_weights_kernel<<<576, 256, 0, stream>>>(gcw, W, gtT, WT);
    rot_table_kernel<<<1024, 256, 0, stream>>>(R, cosT, sinT);
    build_x0_kernel<<<dim3(4, 16, 16), 256, 0, stream>>>(inp, hs, xRow, xT0);

    att_partial_kernel<<<dim3(64, 8), 256, 0, stream>>>(hs, cosT, sinT, attw, part);
    att_softmax_kernel<<<1, 64, 0, stream>>>(part, attb, wa);
    att_compute_kernel<<<8192, 256, 0, stream>>>(hs, cosT, sinT, wa, attB);

    gco_mfma_kernel<<<dim3(1, 128), 256, 0, stream>>>(xRow, gtT + 0 * 32768, gcb, gcoF, gcoB, 0);
    cheb_mfma_kernel<<<dim3(2, 8, 16), 256, 0, stream>>>(Sbf, xT0, nullptr, xT1, xRow, 1.0f);
    gco_mfma_kernel<<<dim3(1, 128), 256, 0, stream>>>(xRow, gtT + 1 * 32768, gcb, gcoF, gcoB, 1);
    cheb_mfma_kernel<<<dim3(2, 8, 16), 256, 0, stream>>>(Sbf, xT1, xT0, xT2, xRow, 2.0f);
    gco_mfma_kernel<<<dim3(1, 128), 256, 0, stream>>>(xRow, gtT + 2 * 32768, gcb, gcoF, gcoB, 2);
    cheb_mfma_kernel<<<dim3(2, 8, 16), 256, 0, stream>>>(Sbf, xT2, xT1, nullptr, xRow, 2.0f);
    gco_mfma_kernel<<<dim3(1, 128), 256, 0, stream>>>(xRow, gtT + 3 * 32768, gcb, gcoF, gcoB, 3);

    // S_bf (in newh region) is dead now -> safe to write new_hidden
    copy_hidden_kernel<<<6144, 256, 0, stream>>>((const float4*)hs, (float4*)newh);
    final_mfma_kernel<<<dim3(1, 128), 256, 0, stream>>>(gcoB, WT, bvec, attB, out, newh);
}

// Round 3
// 417.916 us; speedup vs baseline: 1.6316x; 1.0816x over previous
//
#include <hip/hip_runtime.h>
#include <cstddef>

// Shapes: BS=16, N=1024, HID=64, D=128, F=128, C=256, NM=4, PREK=4
constexpr float PHASE_SCALE = (float)(3.141592653589793 / ((12.0 + 2.0) / 64.0));

typedef __bf16 bf16;
typedef __bf16 bf16x4 __attribute__((ext_vector_type(4)));
typedef __bf16 bf16x8 __attribute__((ext_vector_type(8)));
typedef float floatx4 __attribute__((ext_vector_type(4)));

// ---------------- fused prep: S->bf16, rot tables, weight transposes ----------------
// blocks [0,16384): s_convert ; [16384,17408): rot ; [17408,17984): weights
__global__ __launch_bounds__(256) void prep_kernel(
    const float4* __restrict__ S, bf16* __restrict__ Sbf,
    const float* __restrict__ R, float* __restrict__ cosT, float* __restrict__ sinT,
    const float* __restrict__ gcw, const float* __restrict__ W,
    bf16* __restrict__ gtT, bf16* __restrict__ WT)
{
    int bid = blockIdx.x;
    if (bid < 16384) {
        int gi = bid * 256 + threadIdx.x;          // 4,194,304 float4 items
        float4 v = S[gi];
        bf16x4 o;
        o[0] = (bf16)v.x; o[1] = (bf16)v.y; o[2] = (bf16)v.z; o[3] = (bf16)v.w;
        *(bf16x4*)(Sbf + (size_t)gi * 4) = o;
    } else if (bid < 17408) {
        int gi = (bid - 16384) * 256 + threadIdx.x; // 262,144
        float ph = R[gi] * PHASE_SCALE;
        float s, c;
        sincosf(ph, &s, &c);
        cosT[gi] = c;
        sinT[gi] = s;
    } else {
        int gi = (bid - 17408) * 256 + threadIdx.x; // 147,456
        if (gi < 131072) {
            int m = gi >> 15;
            int rem = gi & 32767;
            int d = rem >> 8;
            int c = rem & 255;
            gtT[gi] = (bf16)gcw[(size_t)d * 1024 + c * 4 + m];   // gtT[m][d][c]
        } else {
            int r = gi - 131072;
            int n = r >> 7, k = r & 127;
            WT[r] = (bf16)W[(size_t)k * 128 + n];                // WT[n][k]
        }
    }
}

// ---------------- build x0 (bf16 row-major + transposed) via LDS transpose ----------------
__global__ __launch_bounds__(256) void build_x0_kernel(
    const float* __restrict__ inp, const float* __restrict__ hs,
    bf16* __restrict__ xRow, bf16* __restrict__ xT0)
{
    __shared__ bf16 tile[64][65];
    const int b = blockIdx.z, n0 = blockIdx.y * 64, c0 = blockIdx.x * 64;
    const int tid = threadIdx.x;
    #pragma unroll
    for (int it = 0; it < 16; ++it) {
        int idx = it * 256 + tid;
        int cl = idx & 63, nl = idx >> 6;
        int n = n0 + nl, c = c0 + cl;
        const float* irow = inp + ((size_t)b * 1024 + n) * 128;
        const float* prow = hs + (((size_t)b * 4 + 3) * 1024 + n) * 128;
        float v;
        if (c < 64)       v = irow[c];
        else if (c < 128) v = prow[c - 64];
        else if (c < 192) v = irow[c - 64];
        else              v = prow[c - 128];
        bf16 vb = (bf16)v;
        xRow[((size_t)b * 1024 + n) * 256 + c] = vb;
        tile[nl][cl] = vb;
    }
    __syncthreads();
    #pragma unroll
    for (int it = 0; it < 16; ++it) {
        int idx = it * 256 + tid;
        int nl = idx & 63, cl = idx >> 6;
        xT0[((size_t)b * 256 + c0 + cl) * 1024 + n0 + nl] = tile[nl][cl];
    }
}

// -------- attention partial sums over n-chunks --------
__global__ __launch_bounds__(256) void att_partial_kernel(
    const float* __restrict__ hs, const float* __restrict__ cosT,
    const float* __restrict__ sinT, const float* __restrict__ attw,
    float* __restrict__ part)
{
    int bk = blockIdx.x;            // b*4+k
    int k = bk & 3;
    int chunk = blockIdx.y;         // 0..7
    const float* hbase = hs + (size_t)bk * 1024 * 128;
    float acc = 0.f;
    for (int idx = threadIdx.x; idx < 128 * 64; idx += 256) {
        int h = idx & 63;
        int n = chunk * 128 + (idx >> 6);
        float c = cosT[(size_t)k * 65536 + n * 64 + h];
        float s = sinT[(size_t)k * 65536 + n * 64 + h];
        float re = hbase[(size_t)n * 128 + h];
        float im = hbase[(size_t)n * 128 + 64 + h];
        float rn = c * re - s * im;
        float in_ = s * re + c * im;
        acc += rn * attw[n * 128 + h] + in_ * attw[n * 128 + 64 + h];
    }
    __shared__ float red[256];
    red[threadIdx.x] = acc;
    __syncthreads();
    for (int s2 = 128; s2 > 0; s2 >>= 1) {
        if (threadIdx.x < (unsigned)s2) red[threadIdx.x] += red[threadIdx.x + s2];
        __syncthreads();
    }
    if (threadIdx.x == 0) part[bk * 8 + chunk] = red[0];
}

__global__ __launch_bounds__(64) void att_softmax_kernel(
    const float* __restrict__ part, const float* __restrict__ attb, float* __restrict__ wa)
{
    int b = threadIdx.x;
    if (b >= 16) return;
    float sa[4];
    float mx = -1e30f;
    for (int k = 0; k < 4; ++k) {
        float s = attb[0];
        for (int c = 0; c < 8; ++c) s += part[(b * 4 + k) * 8 + c];
        sa[k] = s;
        mx = fmaxf(mx, s);
    }
    float den = 0.f;
    for (int k = 0; k < 4; ++k) { sa[k] = expf(sa[k] - mx); den += sa[k]; }
    for (int k = 0; k < 4; ++k) wa[b * 4 + k] = sa[k] / den;
}

// -------- att compute + copy hs[:,1:] -> newh[:, :3] (fused; runs after cheb3) --------
__global__ __launch_bounds__(256) void att_compute_copy_kernel(
    const float* __restrict__ hs, const float* __restrict__ cosT,
    const float* __restrict__ sinT, const float* __restrict__ wa,
    float* __restrict__ attB, float* __restrict__ newh)
{
    int gi = blockIdx.x * 256 + threadIdx.x;      // 16*1024*128
    int d = gi & 127;
    int n = (gi >> 7) & 1023;
    int b = gi >> 17;
    int h = d & 63;
    bool isre = (d < 64);
    float acc = 0.f;
    #pragma unroll
    for (int k = 0; k < 4; ++k) {
        float c = cosT[(size_t)k * 65536 + n * 64 + h];
        float s = sinT[(size_t)k * 65536 + n * 64 + h];
        const float* hb = hs + ((((size_t)b * 4 + k) * 1024 + n) * 128);
        float re = hb[h];
        float im = hb[64 + h];
        float v = isre ? (c * re - s * im) : (s * re + c * im);
        acc += wa[b * 4 + k] * v;
        if (k >= 1) {
            // new_hidden[b][k-1][n][d] = hidden_states[b][k][n][d]
            newh[(size_t)b * 524288 + (size_t)(k - 1) * 131072 + (size_t)n * 128 + d]
                = isre ? re : im;
        }
    }
    attB[gi] = acc;
}

// ---------------- Chebyshev MFMA + fused gco accumulation ----------------
// Per batch: xnext[n][c] = alpha*(S@x)[n][c] - xprev ; gcoF[n][d] += xnext @ gt^T (atomic)
// Tile: 64 rows x 128 cols, grid (2,16,16) = 512 blocks, 4 waves, wave = 32x64.
__global__ __launch_bounds__(256) void cheb_mfma_kernel(
    const bf16* __restrict__ S, const bf16* __restrict__ xT,
    const bf16* __restrict__ xTprev, bf16* __restrict__ outT,
    const bf16* __restrict__ gt, float* __restrict__ gcoF, float alpha)
{
    __shared__ bf16 tileL[64 * 136];
    const int b = blockIdx.z;
    const int c0 = blockIdx.x * 128;
    const int n0 = blockIdx.y * 64;
    const int tid = threadIdx.x;
    const int wave = tid >> 6, lane = tid & 63;
    const int wr = (wave >> 1) * 32, wc = (wave & 1) * 64;
    const int l15 = lane & 15, quad = lane >> 4;

    const bf16* Sb = S + (size_t)b * 1048576;
    const bf16* xb = xT + (size_t)b * 262144;

    const bf16* aptr[2];
    const bf16* bptr[4];
    int colL[4];
    #pragma unroll
    for (int t = 0; t < 2; ++t)
        aptr[t] = Sb + (size_t)(n0 + wr + t * 16 + l15) * 1024 + quad * 8;
    #pragma unroll
    for (int j = 0; j < 4; ++j) {
        colL[j] = wc + j * 16 + l15;
        bptr[j] = xb + (size_t)(c0 + colL[j]) * 1024 + quad * 8;
    }

    floatx4 acc[2][4] = {};
    for (int k0 = 0; k0 < 1024; k0 += 32) {
        bf16x8 af[2], bfr[4];
        #pragma unroll
        for (int t = 0; t < 2; ++t) af[t] = *(const bf16x8*)(aptr[t] + k0);
        #pragma unroll
        for (int j = 0; j < 4; ++j) bfr[j] = *(const bf16x8*)(bptr[j] + k0);
        #pragma unroll
        for (int i = 0; i < 2; ++i)
            #pragma unroll
            for (int j = 0; j < 4; ++j)
                acc[i][j] = __builtin_amdgcn_mfma_f32_16x16x32_bf16(af[i], bfr[j], acc[i][j], 0, 0, 0);
    }

    // epilogue: xnext = alpha*acc - xprev -> bf16; write outT (if any) + LDS tile
    const bf16* pT = xTprev ? xTprev + (size_t)b * 262144 : nullptr;
    bf16* oT = outT ? outT + (size_t)b * 262144 : nullptr;
    #pragma unroll
    for (int i = 0; i < 2; ++i) {
        int rL = wr + i * 16 + quad * 4;              // local row base (4 consecutive)
        #pragma unroll
        for (int j = 0; j < 4; ++j) {
            int cl = colL[j];
            int cg = c0 + cl;
            float v[4];
            #pragma unroll
            for (int r = 0; r < 4; ++r) v[r] = alpha * acc[i][j][r];
            if (pT) {
                const bf16* pp = pT + (size_t)cg * 1024 + n0 + rL;
                #pragma unroll
                for (int r = 0; r < 4; ++r) v[r] -= (float)pp[r];
            }
            bf16x4 o;
            #pragma unroll
            for (int r = 0; r < 4; ++r) o[r] = (bf16)v[r];
            if (oT) *(bf16x4*)(oT + (size_t)cg * 1024 + n0 + rL) = o;
            #pragma unroll
            for (int r = 0; r < 4; ++r) tileL[(rL + r) * 136 + cl] = o[r];
        }
    }
    __syncthreads();

    // gco stage: this block's 64 rows x 128 c-slice vs gt[d][c] -> atomic into gcoF
    const bf16* abase = tileL + (wave * 16 + l15) * 136 + quad * 8;
    const bf16* gptr[8];
    #pragma unroll
    for (int j = 0; j < 8; ++j)
        gptr[j] = gt + (size_t)(j * 16 + l15) * 256 + c0 + quad * 8;
    floatx4 acc2[8] = {};
    for (int k2 = 0; k2 < 128; k2 += 32) {
        bf16x8 afr = *(const bf16x8*)(abase + k2);
        #pragma unroll
        for (int j = 0; j < 8; ++j) {
            bf16x8 bfr = *(const bf16x8*)(gptr[j] + k2);
            acc2[j] = __builtin_amdgcn_mfma_f32_16x16x32_bf16(afr, bfr, acc2[j], 0, 0, 0);
        }
    }
    #pragma unroll
    for (int j = 0; j < 8; ++j) {
        int dcol = j * 16 + l15;
        #pragma unroll
        for (int r = 0; r < 4; ++r) {
            int row = n0 + wave * 16 + quad * 4 + r;
            atomicAdd(&gcoF[((size_t)b * 1024 + row) * 128 + dcol], acc2[j][r]);
        }
    }
}

// ---------------- gco0: gcoF = x0 @ gt0^T (init, plain store) ----------------
// M=16384, K=256, N=128; 64-row tiles -> 256 blocks, 4 waves x 16 rows
__global__ __launch_bounds__(256) void gco0_kernel(
    const bf16* __restrict__ xRow, const bf16* __restrict__ gt0,
    float* __restrict__ gcoF)
{
    const int m0 = blockIdx.x * 64;
    const int tid = threadIdx.x;
    const int wave = tid >> 6, lane = tid & 63;
    const int l15 = lane & 15, quad = lane >> 4;

    const bf16* abase = xRow + (size_t)(m0 + wave * 16 + l15) * 256 + quad * 8;
    const bf16* gptr[8];
    #pragma unroll
    for (int j = 0; j < 8; ++j)
        gptr[j] = gt0 + (size_t)(j * 16 + l15) * 256 + quad * 8;
    floatx4 acc[8] = {};
    for (int k0 = 0; k0 < 256; k0 += 32) {
        bf16x8 afr = *(const bf16x8*)(abase + k0);
        #pragma unroll
        for (int j = 0; j < 8; ++j) {
            bf16x8 bfr = *(const bf16x8*)(gptr[j] + k0);
            acc[j] = __builtin_amdgcn_mfma_f32_16x16x32_bf16(afr, bfr, acc[j], 0, 0, 0);
        }
    }
    #pragma unroll
    for (int j = 0; j < 8; ++j) {
        int dcol = j * 16 + l15;
        #pragma unroll
        for (int r = 0; r < 4; ++r) {
            int row = m0 + wave * 16 + quad * 4 + r;
            gcoF[(size_t)row * 128 + dcol] = acc[j][r];
        }
    }
}

// ---------------- final: out = leaky(gcoF + gcb) @ WT^T + b + att ----------------
__global__ __launch_bounds__(256) void final_mfma_kernel(
    const float* __restrict__ gcoF, const float* __restrict__ gcb,
    const bf16* __restrict__ WT, const float* __restrict__ bvec,
    const float* __restrict__ attB, float* __restrict__ out, float* __restrict__ newh)
{
    const int m0 = blockIdx.x * 64;
    const int tid = threadIdx.x;
    const int wave = tid >> 6, lane = tid & 63;
    const int l15 = lane & 15, quad = lane >> 4;

    const float* abase = gcoF + (size_t)(m0 + wave * 16 + l15) * 128 + quad * 8;
    const float* gbase = gcb + quad * 8;
    const bf16* gptr[8];
    #pragma unroll
    for (int j = 0; j < 8; ++j)
        gptr[j] = WT + (size_t)(j * 16 + l15) * 128 + quad * 8;
    floatx4 acc[8] = {};
    for (int k0 = 0; k0 < 128; k0 += 32) {
        float4 p0 = *(const float4*)(abase + k0);
        float4 p1 = *(const float4*)(abase + k0 + 4);
        float4 g0 = *(const float4*)(gbase + k0);
        float4 g1 = *(const float4*)(gbase + k0 + 4);
        float vv[8] = {p0.x + g0.x, p0.y + g0.y, p0.z + g0.z, p0.w + g0.w,
                       p1.x + g1.x, p1.y + g1.y, p1.z + g1.z, p1.w + g1.w};
        bf16x8 afr;
        #pragma unroll
        for (int e = 0; e < 8; ++e) {
            float v = vv[e];
            v = v >= 0.f ? v : 0.01f * v;
            afr[e] = (bf16)v;
        }
        #pragma unroll
        for (int j = 0; j < 8; ++j) {
            bf16x8 bfr = *(const bf16x8*)(gptr[j] + k0);
            acc[j] = __builtin_amdgcn_mfma_f32_16x16x32_bf16(afr, bfr, acc[j], 0, 0, 0);
        }
    }
    #pragma unroll
    for (int j = 0; j < 8; ++j) {
        int col = j * 16 + l15;
        #pragma unroll
        for (int r = 0; r < 4; ++r) {
            int row = m0 + wave * 16 + quad * 4 + r;
            int bidx = row >> 10, n = row & 1023;
            float o = acc[j][r] + bvec[(size_t)n * 128 + col] + attB[(size_t)row * 128 + col];
            out[(size_t)row * 128 + col] = o;
            newh[(size_t)bidx * 524288 + 393216 + (size_t)n * 128 + col] = o;
        }
    }
}

extern "C" void kernel_launch(void* const* d_in, const int* in_sizes, int n_in,
                              void* d_out, int out_size, void* d_ws, size_t ws_size,
                              hipStream_t stream) {
    const float* inp  = (const float*)d_in[0];
    const float* sup  = (const float*)d_in[1];
    const float* hs   = (const float*)d_in[2];
    const float* W    = (const float*)d_in[3];
    const float* bvec = (const float*)d_in[4];
    const float* R    = (const float*)d_in[5];
    const float* gcw  = (const float*)d_in[6];
    const float* gcb  = (const float*)d_in[7];
    // d_in[8], d_in[9] (ev_att_w/b) dead: softmax over size-1 axis == 1
    const float* attw = (const float*)d_in[10];
    const float* attb = (const float*)d_in[11];

    float* out  = (float*)d_out;                    // (16,1024,128)
    float* newh = out + 2097152;                    // (16,4,1024,128) = 33.5 MB
    bf16*  Sbf  = (bf16*)newh;                      // S bf16 lives here until att_compute_copy

    char* w = (char*)d_ws;
    bf16*  xT0  = (bf16*)(w);                       // 8 MB  [16][256][1024]
    bf16*  xT1  = (bf16*)(w + 8388608);             // 8 MB
    bf16*  xT2  = (bf16*)(w + 16777216);            // 8 MB
    bf16*  xRow = (bf16*)(w + 25165824);            // 8 MB  [16384][256]
    float* gcoF = (float*)(w + 33554432);           // 8 MB  [16384][128]
    bf16*  gtT  = (bf16*)(w + 41943040);            // 256 KB [4][128][256]
    bf16*  WT   = (bf16*)(w + 42205184);            // 32 KB [128][128]
    float* cosT = (float*)(w + 42237952);           // 1 MB
    float* sinT = (float*)(w + 43286528);           // 1 MB
    float* attB = (float*)(w + 44335104);           // 8 MB
    float* part = (float*)(w + 52723712);           // 2 KB
    float* wa   = (float*)(w + 52725760);           // 64 B
    // total ~52.7 MB

    prep_kernel<<<17984, 256, 0, stream>>>((const float4*)sup, Sbf, R, cosT, sinT,
                                           gcw, W, gtT, WT);
    build_x0_kernel<<<dim3(4, 16, 16), 256, 0, stream>>>(inp, hs, xRow, xT0);
    att_partial_kernel<<<dim3(64, 8), 256, 0, stream>>>(hs, cosT, sinT, attw, part);
    att_softmax_kernel<<<1, 64, 0, stream>>>(part, attb, wa);

    gco0_kernel<<<256, 256, 0, stream>>>(xRow, gtT + 0 * 32768, gcoF);
    cheb_mfma_kernel<<<dim3(2, 16, 16), 256, 0, stream>>>(Sbf, xT0, nullptr, xT1,
                                                          gtT + 1 * 32768, gcoF, 1.0f);
    cheb_mfma_kernel<<<dim3(2, 16, 16), 256, 0, stream>>>(Sbf, xT1, xT0, xT2,
                                                          gtT + 2 * 32768, gcoF, 2.0f);
    cheb_mfma_kernel<<<dim3(2, 16, 16), 256, 0, stream>>>(Sbf, xT2, xT1, nullptr,
                                                          gtT + 3 * 32768, gcoF, 2.0f);

    // Sbf (in newh region) is dead now -> safe to write new_hidden
    att_compute_copy_kernel<<<8192, 256, 0, stream>>>(hs, cosT, sinT, wa, attB, newh);
    final_mfma_kernel<<<256, 256, 0, stream>>>(gcoF, gcb, WT, bvec, attB, out, newh);
}

// Round 4
// 396.675 us; speedup vs baseline: 1.7190x; 1.0535x over previous
//
#include <hip/hip_runtime.h>
#include <cstddef>

// Shapes: BS=16, N=1024, HID=64, D=128, F=128, C=256, NM=4, PREK=4
constexpr float PHASE_SCALE = (float)(3.141592653589793 / ((12.0 + 2.0) / 64.0));

typedef __bf16 bf16;
typedef __bf16 bf16x4 __attribute__((ext_vector_type(4)));
typedef __bf16 bf16x8 __attribute__((ext_vector_type(8)));
typedef float floatx4 __attribute__((ext_vector_type(4)));

// ============ fused prep ============
// blocks [0,16384): S fp32->bf16
// [16384,17408): build x0 (xAll slot 0 + xT0)   (4 x 16 x 16 tiles)
// [17408,17920): att partial sums (64 bk x 8 chunks), sincos recomputed
// [17920,18496): weight transposes gtAll / WT
__global__ __launch_bounds__(256) void prep_kernel(
    const float4* __restrict__ S, bf16* __restrict__ Sbf,
    const float* __restrict__ R,
    const float* __restrict__ gcw, const float* __restrict__ W,
    bf16* __restrict__ gtAll, bf16* __restrict__ WT,
    const float* __restrict__ inp, const float* __restrict__ hs,
    bf16* __restrict__ xAll, bf16* __restrict__ xT0,
    const float* __restrict__ attw, float* __restrict__ part)
{
    __shared__ bf16 tile[64][65];
    __shared__ float red[256];
    const int bid = blockIdx.x;
    const int tid = threadIdx.x;

    if (bid < 16384) {
        int gi = bid * 256 + tid;                 // 4,194,304 float4 items
        float4 v = S[gi];
        bf16x4 o;
        o[0] = (bf16)v.x; o[1] = (bf16)v.y; o[2] = (bf16)v.z; o[3] = (bf16)v.w;
        *(bf16x4*)(Sbf + (size_t)gi * 4) = o;
    } else if (bid < 17408) {
        int bid2 = bid - 16384;                   // bx + 4*by + 64*b
        int b = bid2 >> 6;
        int by = (bid2 >> 2) & 15;
        int bx = bid2 & 3;
        int n0 = by * 64, c0 = bx * 64;
        #pragma unroll
        for (int it = 0; it < 16; ++it) {
            int idx = it * 256 + tid;
            int cl = idx & 63, nl = idx >> 6;
            int n = n0 + nl, c = c0 + cl;
            const float* irow = inp + ((size_t)b * 1024 + n) * 128;
            const float* prow = hs + (((size_t)b * 4 + 3) * 1024 + n) * 128;
            float v;
            if (c < 64)       v = irow[c];
            else if (c < 128) v = prow[c - 64];
            else if (c < 192) v = irow[c - 64];
            else              v = prow[c - 128];
            bf16 vb = (bf16)v;
            xAll[((size_t)b * 1024 + n) * 1024 + c] = vb;   // slot m=0
            tile[nl][cl] = vb;
        }
        __syncthreads();
        #pragma unroll
        for (int it = 0; it < 16; ++it) {
            int idx = it * 256 + tid;
            int nl = idx & 63, cl = idx >> 6;
            xT0[((size_t)b * 256 + c0 + cl) * 1024 + n0 + nl] = tile[nl][cl];
        }
    } else if (bid < 17920) {
        int bid3 = bid - 17408;
        int bk = bid3 & 63;                       // b*4+k
        int k = bk & 3;
        int chunk = bid3 >> 6;                    // 0..7
        const float* hbase = hs + (size_t)bk * 131072;
        float acc = 0.f;
        for (int idx = tid; idx < 128 * 64; idx += 256) {
            int h = idx & 63;
            int n = chunk * 128 + (idx >> 6);
            float ph = R[(size_t)k * 65536 + n * 64 + h] * PHASE_SCALE;
            float s, c;
            sincosf(ph, &s, &c);
            float re = hbase[(size_t)n * 128 + h];
            float im = hbase[(size_t)n * 128 + 64 + h];
            float rn = c * re - s * im;
            float in_ = s * re + c * im;
            acc += rn * attw[n * 128 + h] + in_ * attw[n * 128 + 64 + h];
        }
        red[tid] = acc;
        __syncthreads();
        for (int s2 = 128; s2 > 0; s2 >>= 1) {
            if (tid < s2) red[tid] += red[tid + s2];
            __syncthreads();
        }
        if (tid == 0) part[bk * 8 + chunk] = red[0];
    } else {
        int gi = (bid - 17920) * 256 + tid;       // 147,456
        if (gi < 131072) {
            int d = gi >> 10;
            int m = (gi >> 8) & 3;
            int c = gi & 255;
            gtAll[gi] = (bf16)gcw[(size_t)d * 1024 + c * 4 + m];  // gtAll[d][m*256+c]
        } else {
            int r = gi - 131072;
            int n = r >> 7, k = r & 127;
            WT[r] = (bf16)W[(size_t)k * 128 + n];                 // WT[n][k]
        }
    }
}

// ============ Chebyshev MFMA GEMM (no atomics, register double-buffer) ============
// xnext = alpha*(S @ x) - xprev ; writes xT (for next hop) + xAll[.., mslot*256+c]
// tile 64 rows x 128 cols; 512 blocks total, XCD-swizzled so batch b -> XCD b%8.
__global__ __launch_bounds__(256, 2) void cheb_mfma_kernel(
    const bf16* __restrict__ S, const bf16* __restrict__ xT,
    const bf16* __restrict__ xTprev, bf16* __restrict__ outT,
    bf16* __restrict__ xAll, int mslot, float alpha)
{
    const int f = blockIdx.x;
    const int b = (f & 7) + 8 * ((f >> 3) & 1);   // batch -> XCD f%8 locality
    const int t = f >> 4;                         // 0..31 tile within batch
    const int c0 = (t & 1) * 128;
    const int n0 = (t >> 1) * 64;
    const int tid = threadIdx.x;
    const int wave = tid >> 6, lane = tid & 63;
    const int wr = (wave >> 1) * 32, wc = (wave & 1) * 64;
    const int l15 = lane & 15, quad = lane >> 4;

    const bf16* Sb = S + (size_t)b * 1048576;
    const bf16* xb = xT + (size_t)b * 262144;

    const bf16* aptr[2];
    const bf16* bptr[4];
    int colL[4];
    #pragma unroll
    for (int i = 0; i < 2; ++i)
        aptr[i] = Sb + (size_t)(n0 + wr + i * 16 + l15) * 1024 + quad * 8;
    #pragma unroll
    for (int j = 0; j < 4; ++j) {
        colL[j] = wc + j * 16 + l15;
        bptr[j] = xb + (size_t)(c0 + colL[j]) * 1024 + quad * 8;
    }

    floatx4 acc[2][4] = {};
    bf16x8 cA[2], cB[4];
    #pragma unroll
    for (int i = 0; i < 2; ++i) cA[i] = *(const bf16x8*)(aptr[i]);
    #pragma unroll
    for (int j = 0; j < 4; ++j) cB[j] = *(const bf16x8*)(bptr[j]);

    for (int k0 = 0; k0 < 992; k0 += 32) {
        bf16x8 nA[2], nB[4];
        #pragma unroll
        for (int i = 0; i < 2; ++i) nA[i] = *(const bf16x8*)(aptr[i] + k0 + 32);
        #pragma unroll
        for (int j = 0; j < 4; ++j) nB[j] = *(const bf16x8*)(bptr[j] + k0 + 32);
        #pragma unroll
        for (int i = 0; i < 2; ++i)
            #pragma unroll
            for (int j = 0; j < 4; ++j)
                acc[i][j] = __builtin_amdgcn_mfma_f32_16x16x32_bf16(cA[i], cB[j], acc[i][j], 0, 0, 0);
        #pragma unroll
        for (int i = 0; i < 2; ++i) cA[i] = nA[i];
        #pragma unroll
        for (int j = 0; j < 4; ++j) cB[j] = nB[j];
    }
    #pragma unroll
    for (int i = 0; i < 2; ++i)
        #pragma unroll
        for (int j = 0; j < 4; ++j)
            acc[i][j] = __builtin_amdgcn_mfma_f32_16x16x32_bf16(cA[i], cB[j], acc[i][j], 0, 0, 0);

    const bf16* pT = xTprev ? xTprev + (size_t)b * 262144 : nullptr;
    bf16* oT = outT ? outT + (size_t)b * 262144 : nullptr;
    bf16* xr = xAll + (size_t)b * 1048576 + mslot * 256;
    #pragma unroll
    for (int i = 0; i < 2; ++i) {
        int rL = wr + i * 16 + quad * 4;          // 4 consecutive local rows
        #pragma unroll
        for (int j = 0; j < 4; ++j) {
            int cg = c0 + colL[j];
            float v[4];
            #pragma unroll
            for (int r = 0; r < 4; ++r) v[r] = alpha * acc[i][j][r];
            if (pT) {
                const bf16* pp = pT + (size_t)cg * 1024 + n0 + rL;
                #pragma unroll
                for (int r = 0; r < 4; ++r) v[r] -= (float)pp[r];
            }
            bf16x4 o;
            #pragma unroll
            for (int r = 0; r < 4; ++r) o[r] = (bf16)v[r];
            if (oT) *(bf16x4*)(oT + (size_t)cg * 1024 + n0 + rL) = o;
            // coalesced: 16 lanes (l15) = 16 consecutive c for fixed row
            #pragma unroll
            for (int r = 0; r < 4; ++r)
                xr[(size_t)(n0 + rL + r) * 1024 + cg] = o[r];
        }
    }
}

// ============ att compute + softmax + copy hs[:,1:] -> newh[:, :3] ============
__global__ __launch_bounds__(256) void att_compute_copy_kernel(
    const float* __restrict__ hs, const float* __restrict__ R,
    const float* __restrict__ part, const float* __restrict__ attb,
    float* __restrict__ attB, float* __restrict__ newh)
{
    int gi = blockIdx.x * 256 + threadIdx.x;      // 16*1024*128
    int d = gi & 127;
    int n = (gi >> 7) & 1023;
    int b = gi >> 17;
    int h = d & 63;
    bool isre = (d < 64);

    float sa[4], mx = -1e30f;
    #pragma unroll
    for (int k = 0; k < 4; ++k) {
        float s = attb[0];
        #pragma unroll
        for (int c = 0; c < 8; ++c) s += part[(b * 4 + k) * 8 + c];
        sa[k] = s;
        mx = fmaxf(mx, s);
    }
    float den = 0.f;
    #pragma unroll
    for (int k = 0; k < 4; ++k) { sa[k] = __expf(sa[k] - mx); den += sa[k]; }
    float inv = 1.f / den;

    float acc = 0.f;
    #pragma unroll
    for (int k = 0; k < 4; ++k) {
        float ph = R[(size_t)k * 65536 + n * 64 + h] * PHASE_SCALE;
        float s, c;
        sincosf(ph, &s, &c);
        const float* hb = hs + ((((size_t)b * 4 + k) * 1024 + n) * 128);
        float re = hb[h];
        float im = hb[64 + h];
        float v = isre ? (c * re - s * im) : (s * re + c * im);
        acc += (sa[k] * inv) * v;
        if (k >= 1)
            newh[(size_t)b * 524288 + (size_t)(k - 1) * 131072 + (size_t)n * 128 + d]
                = isre ? re : im;
    }
    attB[gi] = acc;
}

// ============ fused gco + final: out = leaky(xAll@gtAll^T + gcb) @ WT^T + b + att ============
// stage1: M=16384, K=1024, N=128 ; LDS transpose ; stage2: K=128
__global__ __launch_bounds__(256, 2) void gco_final_kernel(
    const bf16* __restrict__ xAll, const bf16* __restrict__ gtAll,
    const float* __restrict__ gcb, const bf16* __restrict__ WT,
    const float* __restrict__ bvec, const float* __restrict__ attB,
    float* __restrict__ out, float* __restrict__ newh)
{
    __shared__ bf16 ldsT[64 * 136];
    const int m0 = blockIdx.x * 64;
    const int tid = threadIdx.x;
    const int wave = tid >> 6, lane = tid & 63;
    const int l15 = lane & 15, quad = lane >> 4;

    // ---- stage 1: gco rows m0..m0+63 ----
    const bf16* ap = xAll + (size_t)(m0 + wave * 16 + l15) * 1024 + quad * 8;
    const bf16* bp[8];
    #pragma unroll
    for (int j = 0; j < 8; ++j)
        bp[j] = gtAll + (size_t)(j * 16 + l15) * 1024 + quad * 8;

    floatx4 a1[8] = {};
    bf16x8 cA = *(const bf16x8*)ap;
    bf16x8 cB[8];
    #pragma unroll
    for (int j = 0; j < 8; ++j) cB[j] = *(const bf16x8*)(bp[j]);
    for (int k0 = 0; k0 < 992; k0 += 32) {
        bf16x8 nA = *(const bf16x8*)(ap + k0 + 32);
        bf16x8 nB[8];
        #pragma unroll
        for (int j = 0; j < 8; ++j) nB[j] = *(const bf16x8*)(bp[j] + k0 + 32);
        #pragma unroll
        for (int j = 0; j < 8; ++j)
            a1[j] = __builtin_amdgcn_mfma_f32_16x16x32_bf16(cA, cB[j], a1[j], 0, 0, 0);
        cA = nA;
        #pragma unroll
        for (int j = 0; j < 8; ++j) cB[j] = nB[j];
    }
    #pragma unroll
    for (int j = 0; j < 8; ++j)
        a1[j] = __builtin_amdgcn_mfma_f32_16x16x32_bf16(cA, cB[j], a1[j], 0, 0, 0);

    // bias + leaky -> LDS (transpose to A-operand layout)
    #pragma unroll
    for (int j = 0; j < 8; ++j) {
        int dcol = j * 16 + l15;
        float g = gcb[dcol];
        #pragma unroll
        for (int r = 0; r < 4; ++r) {
            int lrow = wave * 16 + quad * 4 + r;
            float v = a1[j][r] + g;
            v = v >= 0.f ? v : 0.01f * v;
            ldsT[lrow * 136 + dcol] = (bf16)v;
        }
    }
    __syncthreads();

    // ---- stage 2: @ W ----
    const bf16* wp[8];
    #pragma unroll
    for (int j = 0; j < 8; ++j)
        wp[j] = WT + (size_t)(j * 16 + l15) * 128 + quad * 8;
    const bf16* lp = ldsT + (wave * 16 + l15) * 136 + quad * 8;
    floatx4 a2[8] = {};
    #pragma unroll
    for (int k0 = 0; k0 < 128; k0 += 32) {
        bf16x8 af = *(const bf16x8*)(lp + k0);
        #pragma unroll
        for (int j = 0; j < 8; ++j) {
            bf16x8 bfr = *(const bf16x8*)(wp[j] + k0);
            a2[j] = __builtin_amdgcn_mfma_f32_16x16x32_bf16(af, bfr, a2[j], 0, 0, 0);
        }
    }
    #pragma unroll
    for (int j = 0; j < 8; ++j) {
        int col = j * 16 + l15;
        #pragma unroll
        for (int r = 0; r < 4; ++r) {
            int row = m0 + wave * 16 + quad * 4 + r;
            int bidx = row >> 10, n = row & 1023;
            float o = a2[j][r] + bvec[(size_t)n * 128 + col] + attB[(size_t)row * 128 + col];
            out[(size_t)row * 128 + col] = o;
            newh[(size_t)bidx * 524288 + 393216 + (size_t)n * 128 + col] = o;
        }
    }
}

extern "C" void kernel_launch(void* const* d_in, const int* in_sizes, int n_in,
                              void* d_out, int out_size, void* d_ws, size_t ws_size,
                              hipStream_t stream) {
    const float* inp  = (const float*)d_in[0];
    const float* sup  = (const float*)d_in[1];
    const float* hs   = (const float*)d_in[2];
    const float* W    = (const float*)d_in[3];
    const float* bvec = (const float*)d_in[4];
    const float* R    = (const float*)d_in[5];
    const float* gcw  = (const float*)d_in[6];
    const float* gcb  = (const float*)d_in[7];
    // d_in[8], d_in[9] (ev_att_w/b) dead: softmax over size-1 axis == 1
    const float* attw = (const float*)d_in[10];
    const float* attb = (const float*)d_in[11];

    float* out  = (float*)d_out;                    // (16,1024,128)
    float* newh = out + 2097152;                    // (16,4,1024,128) = 33.5 MB
    bf16*  Sbf  = (bf16*)newh;                      // S bf16 here until att_compute_copy

    char* w = (char*)d_ws;
    bf16*  xAll  = (bf16*)(w);                      // 32 MB  [16*1024][1024] (4 hop slots)
    bf16*  xTA   = (bf16*)(w + 33554432);           // 8 MB   [16][256][1024]
    bf16*  xTB   = (bf16*)(w + 41943040);           // 8 MB
    bf16*  gtAll = (bf16*)(w + 50331648);           // 256 KB [128][1024]
    bf16*  WT    = (bf16*)(w + 50593792);           // 32 KB  [128][128]
    float* attB  = (float*)(w + 50626560);          // 8 MB
    float* part  = (float*)(w + 59015168);          // 2 KB
    // total ~59.0 MB (<= 67.6 MB known-safe)

    prep_kernel<<<18496, 256, 0, stream>>>((const float4*)sup, Sbf, R, gcw, W,
                                           gtAll, WT, inp, hs, xAll, xTA, attw, part);

    // x1 = S@x0            ; xTB <- x1T, xAll slot1
    cheb_mfma_kernel<<<512, 256, 0, stream>>>(Sbf, xTA, nullptr, xTB, xAll, 1, 1.0f);
    // x2 = 2S@x1 - x0      ; xTA <- x2T (aliases prev: per-element read-before-write), slot2
    cheb_mfma_kernel<<<512, 256, 0, stream>>>(Sbf, xTB, xTA, xTA, xAll, 2, 2.0f);
    // x3 = 2S@x2 - x1      ; no T output, slot3
    cheb_mfma_kernel<<<512, 256, 0, stream>>>(Sbf, xTA, xTB, nullptr, xAll, 3, 2.0f);

    // Sbf (in newh region) dead now -> safe to write new_hidden
    att_compute_copy_kernel<<<8192, 256, 0, stream>>>(hs, R, part, attb, attB, newh);
    gco_final_kernel<<<256, 256, 0, stream>>>(xAll, gtAll, gcb, WT, bvec, attB, out, newh);
}

// Round 5
// 281.414 us; speedup vs baseline: 2.4231x; 1.4096x over previous
//
#include <hip/hip_runtime.h>
#include <cstddef>

// Shapes: BS=16, N=1024, HID=64, D=128, F=128, C=256, NM=4, PREK=4
constexpr float PHASE_SCALE = (float)(3.141592653589793 / ((12.0 + 2.0) / 64.0));

typedef __bf16 bf16;
typedef __bf16 bf16x4 __attribute__((ext_vector_type(4)));
typedef __bf16 bf16x8 __attribute__((ext_vector_type(8)));
typedef float floatx4 __attribute__((ext_vector_type(4)));

// ============ fused prep ============
// blocks [0,8192): S fp32->bf16 (2 float4/thread)
// [8192,9216): build x0 (xAll slot 0 + xT0)
// [9216,9728): att partial sums (64 bk x 8 chunks), fast sincos
// [9728,10304): weight transposes gtAll / WT
__global__ __launch_bounds__(256) void prep_kernel(
    const float4* __restrict__ S, bf16* __restrict__ Sbf,
    const float* __restrict__ R,
    const float* __restrict__ gcw, const float* __restrict__ W,
    bf16* __restrict__ gtAll, bf16* __restrict__ WT,
    const float* __restrict__ inp, const float* __restrict__ hs,
    bf16* __restrict__ xAll, bf16* __restrict__ xT0,
    const float* __restrict__ attw, float* __restrict__ part)
{
    __shared__ bf16 tile[64][65];
    __shared__ float red[256];
    const int bid = blockIdx.x;
    const int tid = threadIdx.x;

    if (bid < 8192) {
        int gi = bid * 256 + tid;                 // 2 of 4,194,304 float4 items
        #pragma unroll
        for (int it = 0; it < 2; ++it) {
            int idx = gi + it * 2097152;
            float4 v = S[idx];
            bf16x4 o;
            o[0] = (bf16)v.x; o[1] = (bf16)v.y; o[2] = (bf16)v.z; o[3] = (bf16)v.w;
            *(bf16x4*)(Sbf + (size_t)idx * 4) = o;
        }
    } else if (bid < 9216) {
        int bid2 = bid - 8192;                    // bx + 4*by + 64*b
        int b = bid2 >> 6;
        int by = (bid2 >> 2) & 15;
        int bx = bid2 & 3;
        int n0 = by * 64, c0 = bx * 64;
        #pragma unroll
        for (int it = 0; it < 16; ++it) {
            int idx = it * 256 + tid;
            int cl = idx & 63, nl = idx >> 6;
            int n = n0 + nl, c = c0 + cl;
            const float* irow = inp + ((size_t)b * 1024 + n) * 128;
            const float* prow = hs + (((size_t)b * 4 + 3) * 1024 + n) * 128;
            float v;
            if (c < 64)       v = irow[c];
            else if (c < 128) v = prow[c - 64];
            else if (c < 192) v = irow[c - 64];
            else              v = prow[c - 128];
            bf16 vb = (bf16)v;
            xAll[((size_t)b * 1024 + n) * 1024 + c] = vb;   // slot m=0
            tile[nl][cl] = vb;
        }
        __syncthreads();
        #pragma unroll
        for (int it = 0; it < 16; ++it) {
            int idx = it * 256 + tid;
            int nl = idx & 63, cl = idx >> 6;
            xT0[((size_t)b * 256 + c0 + cl) * 1024 + n0 + nl] = tile[nl][cl];
        }
    } else if (bid < 9728) {
        int bid3 = bid - 9216;
        int bk = bid3 & 63;                       // b*4+k
        int k = bk & 3;
        int chunk = bid3 >> 6;                    // 0..7
        const float* hbase = hs + (size_t)bk * 131072;
        float acc = 0.f;
        for (int idx = tid; idx < 2048; idx += 256) {   // 8 iters, float4
            int h4 = (idx & 15) * 4;
            int n = chunk * 128 + (idx >> 4);
            float4 rr  = *(const float4*)(R + (size_t)k * 65536 + n * 64 + h4);
            float4 re  = *(const float4*)(hbase + (size_t)n * 128 + h4);
            float4 im  = *(const float4*)(hbase + (size_t)n * 128 + 64 + h4);
            float4 wre = *(const float4*)(attw + (size_t)n * 128 + h4);
            float4 wim = *(const float4*)(attw + (size_t)n * 128 + 64 + h4);
            float sv, cv;
            __sincosf(rr.x * PHASE_SCALE, &sv, &cv);
            acc += (cv * re.x - sv * im.x) * wre.x + (sv * re.x + cv * im.x) * wim.x;
            __sincosf(rr.y * PHASE_SCALE, &sv, &cv);
            acc += (cv * re.y - sv * im.y) * wre.y + (sv * re.y + cv * im.y) * wim.y;
            __sincosf(rr.z * PHASE_SCALE, &sv, &cv);
            acc += (cv * re.z - sv * im.z) * wre.z + (sv * re.z + cv * im.z) * wim.z;
            __sincosf(rr.w * PHASE_SCALE, &sv, &cv);
            acc += (cv * re.w - sv * im.w) * wre.w + (sv * re.w + cv * im.w) * wim.w;
        }
        red[tid] = acc;
        __syncthreads();
        for (int s2 = 128; s2 > 0; s2 >>= 1) {
            if (tid < s2) red[tid] += red[tid + s2];
            __syncthreads();
        }
        if (tid == 0) part[bk * 8 + chunk] = red[0];
    } else {
        int gi = (bid - 9728) * 256 + tid;        // 147,456
        if (gi < 131072) {
            int d = gi >> 10;
            int m = (gi >> 8) & 3;
            int c = gi & 255;
            gtAll[gi] = (bf16)gcw[(size_t)d * 1024 + c * 4 + m];  // gtAll[d][m*256+c]
        } else {
            int r = gi - 131072;
            int n = r >> 7, k = r & 127;
            WT[r] = (bf16)W[(size_t)k * 128 + n];                 // WT[n][k]
        }
    }
}

// ============ Chebyshev MFMA GEMM (m97-style LDS staging) ============
// xnext = alpha*(S @ x) - xprev ; writes xT (next hop) + xAll[.., mslot*256+c]
// 64 rows x 128 cols per block; BK=64; 512 blocks (2/CU); 4 waves of 32x64.
// LDS tiles [row][k] unpadded; k-segments XOR-swizzled by (row&7) to keep
// ds_read_b128 at 2-way (free) instead of 16-way bank conflict.
__global__ __launch_bounds__(256) void cheb_mfma_kernel(
    const bf16* __restrict__ S, const bf16* __restrict__ xT,
    const bf16* __restrict__ xTprev, bf16* __restrict__ outT,
    bf16* __restrict__ xAll, int mslot, float alpha)
{
    __shared__ bf16 ldsA[64 * 64];    // 8 KB  [row][kseg swizzled]
    __shared__ bf16 ldsB[128 * 64];   // 16 KB [col][kseg swizzled]
    const int f = blockIdx.x;
    const int b = (f & 7) + 8 * ((f >> 3) & 1);   // batch -> XCD f%8 locality
    const int t = f >> 4;                         // 0..31 tile within batch
    const int c0 = (t & 1) * 128;
    const int n0 = (t >> 1) * 64;
    const int tid = threadIdx.x;
    const int wave = tid >> 6, lane = tid & 63;
    const int wr = (wave >> 1) * 32, wc = (wave & 1) * 64;
    const int l15 = lane & 15, quad = lane >> 4;

    const bf16* Sb = S + (size_t)b * 1048576;
    const bf16* xb = xT + (size_t)b * 262144;

    // staging lane mapping: 8 rows x 8 k-segs (16B each) per instruction
    const int lrow = lane >> 3;                   // 0..7
    const int segsw = (lane & 7) ^ lrow;          // swizzled global k-seg

    floatx4 acc[2][4] = {};

    for (int k0 = 0; k0 < 1024; k0 += 64) {
        #pragma unroll
        for (int u = 0; u < 2; ++u) {             // A: wave stages rows [wave*16, +16)
            int Rr = wave * 16 + u * 8;
            const bf16* gp = Sb + (size_t)(n0 + Rr + lrow) * 1024 + k0 + segsw * 8;
            __builtin_amdgcn_global_load_lds(
                (const __attribute__((address_space(1))) void*)gp,
                (__attribute__((address_space(3))) void*)(ldsA + Rr * 64), 16, 0, 0);
        }
        #pragma unroll
        for (int v = 0; v < 4; ++v) {             // B: wave stages cols [wave*32, +32)
            int Cq = wave * 32 + v * 8;
            const bf16* gp = xb + (size_t)(c0 + Cq + lrow) * 1024 + k0 + segsw * 8;
            __builtin_amdgcn_global_load_lds(
                (const __attribute__((address_space(1))) void*)gp,
                (__attribute__((address_space(3))) void*)(ldsB + Cq * 64), 16, 0, 0);
        }
        __syncthreads();
        #pragma unroll
        for (int ks = 0; ks < 2; ++ks) {
            bf16x8 af[2], bfr[4];
            #pragma unroll
            for (int i = 0; i < 2; ++i) {
                int row = wr + i * 16 + l15;
                int slot = (ks * 4 + quad) ^ (row & 7);
                af[i] = *(const bf16x8*)(ldsA + row * 64 + slot * 8);
            }
            #pragma unroll
            for (int j = 0; j < 4; ++j) {
                int col = wc + j * 16 + l15;
                int slot = (ks * 4 + quad) ^ (col & 7);
                bfr[j] = *(const bf16x8*)(ldsB + col * 64 + slot * 8);
            }
            #pragma unroll
            for (int i = 0; i < 2; ++i)
                #pragma unroll
                for (int j = 0; j < 4; ++j)
                    acc[i][j] = __builtin_amdgcn_mfma_f32_16x16x32_bf16(af[i], bfr[j], acc[i][j], 0, 0, 0);
        }
        __syncthreads();
    }

    const bf16* pT = xTprev ? xTprev + (size_t)b * 262144 : nullptr;
    bf16* oT = outT ? outT + (size_t)b * 262144 : nullptr;
    bf16* xr = xAll + (size_t)b * 1048576 + mslot * 256;
    #pragma unroll
    for (int i = 0; i < 2; ++i) {
        int nb = n0 + wr + i * 16 + quad * 4;     // 4 consecutive n
        #pragma unroll
        for (int j = 0; j < 4; ++j) {
            int cg = c0 + wc + j * 16 + l15;
            float v[4];
            #pragma unroll
            for (int r = 0; r < 4; ++r) v[r] = alpha * acc[i][j][r];
            if (pT) {
                const bf16* pp = pT + (size_t)cg * 1024 + nb;
                #pragma unroll
                for (int r = 0; r < 4; ++r) v[r] -= (float)pp[r];
            }
            bf16x4 o;
            #pragma unroll
            for (int r = 0; r < 4; ++r) o[r] = (bf16)v[r];
            if (oT) *(bf16x4*)(oT + (size_t)cg * 1024 + nb) = o;
            #pragma unroll
            for (int r = 0; r < 4; ++r)
                xr[(size_t)(nb + r) * 1024 + cg] = o[r];
        }
    }
}

// ============ att compute + softmax + copy hs[:,1:] -> newh[:, :3] ============
__global__ __launch_bounds__(256) void att_compute_copy_kernel(
    const float* __restrict__ hs, const float* __restrict__ R,
    const float* __restrict__ part, const float* __restrict__ attb,
    float* __restrict__ attB, float* __restrict__ newh)
{
    int gi = blockIdx.x * 256 + threadIdx.x;      // 16*1024*128
    int d = gi & 127;
    int n = (gi >> 7) & 1023;
    int b = gi >> 17;
    int h = d & 63;
    bool isre = (d < 64);

    float sa[4], mx = -1e30f;
    #pragma unroll
    for (int k = 0; k < 4; ++k) {
        float s = attb[0];
        #pragma unroll
        for (int c = 0; c < 8; ++c) s += part[(b * 4 + k) * 8 + c];
        sa[k] = s;
        mx = fmaxf(mx, s);
    }
    float den = 0.f;
    #pragma unroll
    for (int k = 0; k < 4; ++k) { sa[k] = __expf(sa[k] - mx); den += sa[k]; }
    float inv = 1.f / den;

    float acc = 0.f;
    #pragma unroll
    for (int k = 0; k < 4; ++k) {
        float s, c;
        __sincosf(R[(size_t)k * 65536 + n * 64 + h] * PHASE_SCALE, &s, &c);
        const float* hb = hs + ((((size_t)b * 4 + k) * 1024 + n) * 128);
        float re = hb[h];
        float im = hb[64 + h];
        float v = isre ? (c * re - s * im) : (s * re + c * im);
        acc += (sa[k] * inv) * v;
        if (k >= 1)
            newh[(size_t)b * 524288 + (size_t)(k - 1) * 131072 + (size_t)n * 128 + d]
                = isre ? re : im;
    }
    attB[gi] = acc;
}

// ============ fused gco + final: out = leaky(xAll@gtAll^T + gcb) @ WT^T + b + att ============
__global__ __launch_bounds__(256, 2) void gco_final_kernel(
    const bf16* __restrict__ xAll, const bf16* __restrict__ gtAll,
    const float* __restrict__ gcb, const bf16* __restrict__ WT,
    const float* __restrict__ bvec, const float* __restrict__ attB,
    float* __restrict__ out, float* __restrict__ newh)
{
    __shared__ bf16 ldsT[64 * 136];
    const int m0 = blockIdx.x * 64;
    const int tid = threadIdx.x;
    const int wave = tid >> 6, lane = tid & 63;
    const int l15 = lane & 15, quad = lane >> 4;

    // ---- stage 1: gco rows m0..m0+63, K=1024 ----
    const bf16* ap = xAll + (size_t)(m0 + wave * 16 + l15) * 1024 + quad * 8;
    const bf16* bp[8];
    #pragma unroll
    for (int j = 0; j < 8; ++j)
        bp[j] = gtAll + (size_t)(j * 16 + l15) * 1024 + quad * 8;

    floatx4 a1[8] = {};
    bf16x8 cA = *(const bf16x8*)ap;
    bf16x8 cB[8];
    #pragma unroll
    for (int j = 0; j < 8; ++j) cB[j] = *(const bf16x8*)(bp[j]);
    for (int k0 = 0; k0 < 992; k0 += 32) {
        bf16x8 nA = *(const bf16x8*)(ap + k0 + 32);
        bf16x8 nB[8];
        #pragma unroll
        for (int j = 0; j < 8; ++j) nB[j] = *(const bf16x8*)(bp[j] + k0 + 32);
        #pragma unroll
        for (int j = 0; j < 8; ++j)
            a1[j] = __builtin_amdgcn_mfma_f32_16x16x32_bf16(cA, cB[j], a1[j], 0, 0, 0);
        cA = nA;
        #pragma unroll
        for (int j = 0; j < 8; ++j) cB[j] = nB[j];
    }
    #pragma unroll
    for (int j = 0; j < 8; ++j)
        a1[j] = __builtin_amdgcn_mfma_f32_16x16x32_bf16(cA, cB[j], a1[j], 0, 0, 0);

    // bias + leaky -> LDS (transpose to A-operand layout)
    #pragma unroll
    for (int j = 0; j < 8; ++j) {
        int dcol = j * 16 + l15;
        float g = gcb[dcol];
        #pragma unroll
        for (int r = 0; r < 4; ++r) {
            int lrow = wave * 16 + quad * 4 + r;
            float v = a1[j][r] + g;
            v = v >= 0.f ? v : 0.01f * v;
            ldsT[lrow * 136 + dcol] = (bf16)v;
        }
    }
    __syncthreads();

    // ---- stage 2: @ W, K=128 ----
    const bf16* wp[8];
    #pragma unroll
    for (int j = 0; j < 8; ++j)
        wp[j] = WT + (size_t)(j * 16 + l15) * 128 + quad * 8;
    const bf16* lp = ldsT + (wave * 16 + l15) * 136 + quad * 8;
    floatx4 a2[8] = {};
    #pragma unroll
    for (int k0 = 0; k0 < 128; k0 += 32) {
        bf16x8 af = *(const bf16x8*)(lp + k0);
        #pragma unroll
        for (int j = 0; j < 8; ++j) {
            bf16x8 bfr = *(const bf16x8*)(wp[j] + k0);
            a2[j] = __builtin_amdgcn_mfma_f32_16x16x32_bf16(af, bfr, a2[j], 0, 0, 0);
        }
    }
    #pragma unroll
    for (int j = 0; j < 8; ++j) {
        int col = j * 16 + l15;
        #pragma unroll
        for (int r = 0; r < 4; ++r) {
            int row = m0 + wave * 16 + quad * 4 + r;
            int bidx = row >> 10, n = row & 1023;
            float o = a2[j][r] + bvec[(size_t)n * 128 + col] + attB[(size_t)row * 128 + col];
            out[(size_t)row * 128 + col] = o;
            newh[(size_t)bidx * 524288 + 393216 + (size_t)n * 128 + col] = o;
        }
    }
}

extern "C" void kernel_launch(void* const* d_in, const int* in_sizes, int n_in,
                              void* d_out, int out_size, void* d_ws, size_t ws_size,
                              hipStream_t stream) {
    const float* inp  = (const float*)d_in[0];
    const float* sup  = (const float*)d_in[1];
    const float* hs   = (const float*)d_in[2];
    const float* W    = (const float*)d_in[3];
    const float* bvec = (const float*)d_in[4];
    const float* R    = (const float*)d_in[5];
    const float* gcw  = (const float*)d_in[6];
    const float* gcb  = (const float*)d_in[7];
    // d_in[8], d_in[9] (ev_att_w/b) dead: softmax over size-1 axis == 1
    const float* attw = (const float*)d_in[10];
    const float* attb = (const float*)d_in[11];

    float* out  = (float*)d_out;                    // (16,1024,128)
    float* newh = out + 2097152;                    // (16,4,1024,128) = 33.5 MB
    bf16*  Sbf  = (bf16*)newh;                      // S bf16 here until att_compute_copy

    char* w = (char*)d_ws;
    bf16*  xAll  = (bf16*)(w);                      // 32 MB  [16*1024][1024] (4 hop slots)
    bf16*  xTA   = (bf16*)(w + 33554432);           // 8 MB   [16][256][1024]
    bf16*  xTB   = (bf16*)(w + 41943040);           // 8 MB
    bf16*  gtAll = (bf16*)(w + 50331648);           // 256 KB [128][1024]
    bf16*  WT    = (bf16*)(w + 50593792);           // 32 KB  [128][128]
    float* attB  = (float*)(w + 50626560);          // 8 MB
    float* part  = (float*)(w + 59015168);          // 2 KB
    // total ~59.0 MB

    prep_kernel<<<10304, 256, 0, stream>>>((const float4*)sup, Sbf, R, gcw, W,
                                           gtAll, WT, inp, hs, xAll, xTA, attw, part);

    // x1 = S@x0            ; xTB <- x1T, xAll slot1
    cheb_mfma_kernel<<<512, 256, 0, stream>>>(Sbf, xTA, nullptr, xTB, xAll, 1, 1.0f);
    // x2 = 2S@x1 - x0      ; xTA <- x2T (same-thread read-before-write aliasing), slot2
    cheb_mfma_kernel<<<512, 256, 0, stream>>>(Sbf, xTB, xTA, xTA, xAll, 2, 2.0f);
    // x3 = 2S@x2 - x1      ; no T output, slot3
    cheb_mfma_kernel<<<512, 256, 0, stream>>>(Sbf, xTA, xTB, nullptr, xAll, 3, 2.0f);

    // Sbf (in newh region) dead now -> safe to write new_hidden
    att_compute_copy_kernel<<<8192, 256, 0, stream>>>(hs, R, part, attb, attB, newh);
    gco_final_kernel<<<256, 256, 0, stream>>>(xAll, gtAll, gcb, WT, bvec, attB, out, newh);
}

// Round 6
// 265.038 us; speedup vs baseline: 2.5728x; 1.0618x over previous
//
#include <hip/hip_runtime.h>
#include <cstddef>

// Shapes: BS=16, N=1024, HID=64, D=128, F=128, C=256, NM=4, PREK=4
constexpr float PHASE_SCALE = (float)(3.141592653589793 / ((12.0 + 2.0) / 64.0));

typedef __bf16 bf16;
typedef __bf16 bf16x4 __attribute__((ext_vector_type(4)));
typedef __bf16 bf16x8 __attribute__((ext_vector_type(8)));
typedef float floatx4 __attribute__((ext_vector_type(4)));

#define GLOAD_LDS16(gp, lp) __builtin_amdgcn_global_load_lds( \
    (const __attribute__((address_space(1))) void*)(gp),      \
    (__attribute__((address_space(3))) void*)(lp), 16, 0, 0)

// ============ fused prep (small sections FIRST, streaming convert LAST) ============
// [0,576): weight transposes gtAll/WT ; [576,1088): att partials ;
// [1088,2112): x0 build (xRow + xT0) ; [2112,10304): S fp32->bf16
__global__ __launch_bounds__(256) void prep_kernel(
    const float4* __restrict__ S, bf16* __restrict__ Sbf,
    const float* __restrict__ R,
    const float* __restrict__ gcw, const float* __restrict__ W,
    bf16* __restrict__ gtAll, bf16* __restrict__ WT,
    const float* __restrict__ inp, const float* __restrict__ hs,
    bf16* __restrict__ xRow, bf16* __restrict__ xT0,
    const float* __restrict__ attw, float* __restrict__ part)
{
    __shared__ bf16 tile[64][65];
    __shared__ float red[256];
    const int bid = blockIdx.x;
    const int tid = threadIdx.x;

    if (bid < 576) {
        int gi = bid * 256 + tid;                 // 147,456
        if (gi < 131072) {
            int m = gi >> 15;
            int rem = gi & 32767;
            int d = rem >> 8;
            int c = rem & 255;
            gtAll[gi] = (bf16)gcw[(size_t)d * 1024 + c * 4 + m];  // gtAll[m][d][c]
        } else {
            int r = gi - 131072;
            int n = r >> 7, k = r & 127;
            WT[r] = (bf16)W[(size_t)k * 128 + n];                 // WT[n][k]
        }
    } else if (bid < 1088) {
        int bid3 = bid - 576;
        int bk = bid3 & 63;                       // b*4+k
        int k = bk & 3;
        int chunk = bid3 >> 6;                    // 0..7
        const float* hbase = hs + (size_t)bk * 131072;
        float acc = 0.f;
        for (int idx = tid; idx < 2048; idx += 256) {   // 8 iters, float4
            int h4 = (idx & 15) * 4;
            int n = chunk * 128 + (idx >> 4);
            float4 rr  = *(const float4*)(R + (size_t)k * 65536 + n * 64 + h4);
            float4 re  = *(const float4*)(hbase + (size_t)n * 128 + h4);
            float4 im  = *(const float4*)(hbase + (size_t)n * 128 + 64 + h4);
            float4 wre = *(const float4*)(attw + (size_t)n * 128 + h4);
            float4 wim = *(const float4*)(attw + (size_t)n * 128 + 64 + h4);
            float sv, cv;
            __sincosf(rr.x * PHASE_SCALE, &sv, &cv);
            acc += (cv * re.x - sv * im.x) * wre.x + (sv * re.x + cv * im.x) * wim.x;
            __sincosf(rr.y * PHASE_SCALE, &sv, &cv);
            acc += (cv * re.y - sv * im.y) * wre.y + (sv * re.y + cv * im.y) * wim.y;
            __sincosf(rr.z * PHASE_SCALE, &sv, &cv);
            acc += (cv * re.z - sv * im.z) * wre.z + (sv * re.z + cv * im.z) * wim.z;
            __sincosf(rr.w * PHASE_SCALE, &sv, &cv);
            acc += (cv * re.w - sv * im.w) * wre.w + (sv * re.w + cv * im.w) * wim.w;
        }
        red[tid] = acc;
        __syncthreads();
        for (int s2 = 128; s2 > 0; s2 >>= 1) {
            if (tid < s2) red[tid] += red[tid + s2];
            __syncthreads();
        }
        if (tid == 0) part[bk * 8 + chunk] = red[0];
    } else if (bid < 2112) {
        int bid2 = bid - 1088;                    // bx + 4*by + 64*b
        int b = bid2 >> 6;
        int by = (bid2 >> 2) & 15;
        int bx = bid2 & 3;
        int n0 = by * 64, c0 = bx * 64;
        #pragma unroll
        for (int it = 0; it < 16; ++it) {
            int idx = it * 256 + tid;
            int cl = idx & 63, nl = idx >> 6;
            int n = n0 + nl, c = c0 + cl;
            const float* irow = inp + ((size_t)b * 1024 + n) * 128;
            const float* prow = hs + (((size_t)b * 4 + 3) * 1024 + n) * 128;
            float v;
            if (c < 64)       v = irow[c];
            else if (c < 128) v = prow[c - 64];
            else if (c < 192) v = irow[c - 64];
            else              v = prow[c - 128];
            bf16 vb = (bf16)v;
            xRow[((size_t)b * 1024 + n) * 256 + c] = vb;
            tile[nl][cl] = vb;
        }
        __syncthreads();
        #pragma unroll
        for (int it = 0; it < 16; ++it) {
            int idx = it * 256 + tid;
            int nl = idx & 63, cl = idx >> 6;
            xT0[((size_t)b * 256 + c0 + cl) * 1024 + n0 + nl] = tile[nl][cl];
        }
    } else {
        int gi = (bid - 2112) * 256 + tid;        // 2,097,152 threads x 8 floats
        const float4* Sp = S + (size_t)gi * 2;
        float4 v0 = Sp[0];
        float4 v1 = Sp[1];
        bf16x8 o;
        o[0] = (bf16)v0.x; o[1] = (bf16)v0.y; o[2] = (bf16)v0.z; o[3] = (bf16)v0.w;
        o[4] = (bf16)v1.x; o[5] = (bf16)v1.y; o[6] = (bf16)v1.z; o[7] = (bf16)v1.w;
        *(bf16x8*)(Sbf + (size_t)gi * 8) = o;
    }
}

// ============ Chebyshev MFMA + fused per-hop gco (non-atomic: block owns full rows) ===========
// Block = 64 rows x 256 cols (full C) of one batch. 256 blocks, 8 waves (512 thr).
// LDS double-buffered; global_load_lds staged; one barrier per K-step.
// Epilogue: xnext -> xTout (bf16x4) ; LDS-transpose -> xnext @ gt_h^T (+ x0 @ gt0^T on hop1)
// accumulated into gcoF (plain store hop1, += hops 2/3).
__global__ __launch_bounds__(512) void cheb_mfma_kernel(
    const bf16* __restrict__ S, const bf16* __restrict__ xT,
    const bf16* __restrict__ xTprev, bf16* __restrict__ outT,
    const bf16* __restrict__ xRow0, const bf16* __restrict__ gtA,
    const bf16* __restrict__ gt0, float* __restrict__ gcoF,
    float alpha, int accumulate)
{
    __shared__ char smem[81920];                  // 2 x (A 8KB + B 32KB)
    const int f = blockIdx.x;
    const int b = (f & 7) + 8 * ((f >> 3) & 1);   // batch -> XCD f%8
    const int n0 = (f >> 4) * 64;
    const int tid = threadIdx.x;
    const int wave = tid >> 6, lane = tid & 63;
    const int wr = (wave & 3) * 16;               // 16-row group
    const int wc = (wave >> 2) * 128;             // 128-col half
    const int l15 = lane & 15, quad = lane >> 4;
    const int lrow = lane >> 3;                   // staging: 8 rows x 8 segs
    const int segsw = (lane & 7) ^ lrow;

    const bf16* Sb = S + (size_t)b * 1048576;
    const bf16* xb = xT + (size_t)b * 262144;

    auto stage = [&](int p, int k0) {
        bf16* dA = (bf16*)(smem + p * 40960);
        bf16* dB = dA + 4096;                     // 8192 B after A
        // A: wave stages rows [wave*8, wave*8+8)
        {
            const bf16* gp = Sb + (size_t)(n0 + wave * 8 + lrow) * 1024 + k0 + segsw * 8;
            GLOAD_LDS16(gp, dA + wave * 8 * 64);
        }
        // B: wave stages cols [wave*32, wave*32+32)
        #pragma unroll
        for (int v = 0; v < 4; ++v) {
            int cq = wave * 32 + v * 8;
            const bf16* gp = xb + (size_t)(cq + lrow) * 1024 + k0 + segsw * 8;
            GLOAD_LDS16(gp, dB + cq * 64);
        }
    };

    floatx4 acc[8] = {};
    stage(0, 0);
    int p = 0;
    for (int k0 = 0; k0 < 1024; k0 += 64) {
        __syncthreads();                          // drains DMA of buf p; guards reuse
        if (k0 + 64 < 1024) stage(p ^ 1, k0 + 64);
        const bf16* lA = (const bf16*)(smem + p * 40960);
        const bf16* lB = lA + 4096;
        #pragma unroll
        for (int ks = 0; ks < 2; ++ks) {
            int row = wr + l15;
            int aslot = (ks * 4 + quad) ^ (row & 7);
            bf16x8 af = *(const bf16x8*)(lA + row * 64 + aslot * 8);
            #pragma unroll
            for (int j = 0; j < 8; ++j) {
                int col = wc + j * 16 + l15;
                int bslot = (ks * 4 + quad) ^ (col & 7);
                bf16x8 bfr = *(const bf16x8*)(lB + col * 64 + bslot * 8);
                acc[j] = __builtin_amdgcn_mfma_f32_16x16x32_bf16(af, bfr, acc[j], 0, 0, 0);
            }
        }
        p ^= 1;
    }

    // ---- epilogue: xnext = alpha*acc - xprev ----
    const bf16* pT = xTprev ? xTprev + (size_t)b * 262144 : nullptr;
    bf16* oT = outT ? outT + (size_t)b * 262144 : nullptr;
    bf16x4 xo[8];
    #pragma unroll
    for (int j = 0; j < 8; ++j) {
        int col = wc + j * 16 + l15;
        float v[4];
        #pragma unroll
        for (int r = 0; r < 4; ++r) v[r] = alpha * acc[j][r];
        if (pT) {
            bf16x4 pp = *(const bf16x4*)(pT + (size_t)col * 1024 + n0 + wr + quad * 4);
            #pragma unroll
            for (int r = 0; r < 4; ++r) v[r] -= (float)pp[r];
        }
        #pragma unroll
        for (int r = 0; r < 4; ++r) xo[j][r] = (bf16)v[r];
        if (oT) *(bf16x4*)(oT + (size_t)col * 1024 + n0 + wr + quad * 4) = xo[j];
    }

    // ---- LDS transpose of xnext tile (64 x 256, pad to 264) ----
    __syncthreads();                              // all waves done reading dbuf
    bf16* ldsX = (bf16*)smem;
    #pragma unroll
    for (int j = 0; j < 8; ++j) {
        int col = wc + j * 16 + l15;
        #pragma unroll
        for (int r = 0; r < 4; ++r)
            ldsX[(wr + quad * 4 + r) * 264 + col] = xo[j][r];
    }
    __syncthreads();

    // ---- gco: (xnext tile) @ gt_h^T (+ x0 @ gt0^T on hop1) -> gcoF rows ----
    const int dbase = (wave >> 2) * 64;           // this wave's 64 d-cols
    floatx4 a2[4] = {};
    for (int k2 = 0; k2 < 256; k2 += 32) {
        bf16x8 af = *(const bf16x8*)(ldsX + (wr + l15) * 264 + k2 + quad * 8);
        #pragma unroll
        for (int j = 0; j < 4; ++j) {
            int dcol = dbase + j * 16 + l15;
            bf16x8 bfr = *(const bf16x8*)(gtA + (size_t)dcol * 256 + k2 + quad * 8);
            a2[j] = __builtin_amdgcn_mfma_f32_16x16x32_bf16(af, bfr, a2[j], 0, 0, 0);
        }
    }
    if (xRow0) {                                  // hop1: add x0 @ gt0^T
        for (int k2 = 0; k2 < 256; k2 += 32) {
            bf16x8 af = *(const bf16x8*)(xRow0 + ((size_t)b * 1024 + n0 + wr + l15) * 256 + k2 + quad * 8);
            #pragma unroll
            for (int j = 0; j < 4; ++j) {
                int dcol = dbase + j * 16 + l15;
                bf16x8 bfr = *(const bf16x8*)(gt0 + (size_t)dcol * 256 + k2 + quad * 8);
                a2[j] = __builtin_amdgcn_mfma_f32_16x16x32_bf16(af, bfr, a2[j], 0, 0, 0);
            }
        }
    }
    #pragma unroll
    for (int j = 0; j < 4; ++j) {
        int dcol = dbase + j * 16 + l15;
        #pragma unroll
        for (int r = 0; r < 4; ++r) {
            size_t idx = ((size_t)b * 1024 + n0 + wr + quad * 4 + r) * 128 + dcol;
            if (accumulate) gcoF[idx] += a2[j][r];
            else            gcoF[idx]  = a2[j][r];
        }
    }
}

// ============ final: out = leaky(gcoF+gcb) @ WT^T + b + att ; + newh copy + newh[3] ============
// 256 blocks x 64 rows; no LDS (A-frags built in-register from gcoF).
__global__ __launch_bounds__(256) void final_kernel(
    const float* __restrict__ gcoF, const float* __restrict__ gcb,
    const bf16* __restrict__ WT, const float* __restrict__ bvec,
    const float* __restrict__ hs, const float* __restrict__ R,
    const float* __restrict__ part, const float* __restrict__ attb,
    float* __restrict__ out, float* __restrict__ newh)
{
    const int m0 = blockIdx.x * 64;
    const int b = m0 >> 10, n0 = m0 & 1023;
    const int tid = threadIdx.x;
    const int wave = tid >> 6, lane = tid & 63;
    const int l15 = lane & 15, quad = lane >> 4;

    // ---- phase A: leaky(gcoF+gcb) @ W ----
    const int arow = m0 + wave * 16 + l15;
    floatx4 acc[8] = {};
    #pragma unroll
    for (int k0 = 0; k0 < 128; k0 += 32) {
        int kk = k0 + quad * 8;
        float4 p0 = *(const float4*)(gcoF + (size_t)arow * 128 + kk);
        float4 p1 = *(const float4*)(gcoF + (size_t)arow * 128 + kk + 4);
        float4 g0 = *(const float4*)(gcb + kk);
        float4 g1 = *(const float4*)(gcb + kk + 4);
        float vv[8] = {p0.x + g0.x, p0.y + g0.y, p0.z + g0.z, p0.w + g0.w,
                       p1.x + g1.x, p1.y + g1.y, p1.z + g1.z, p1.w + g1.w};
        bf16x8 af;
        #pragma unroll
        for (int e = 0; e < 8; ++e) {
            float v = vv[e];
            af[e] = (bf16)(v >= 0.f ? v : 0.01f * v);
        }
        #pragma unroll
        for (int j = 0; j < 8; ++j) {
            bf16x8 bfr = *(const bf16x8*)(WT + (size_t)(j * 16 + l15) * 128 + kk);
            acc[j] = __builtin_amdgcn_mfma_f32_16x16x32_bf16(af, bfr, acc[j], 0, 0, 0);
        }
    }

    // ---- softmax weights wa[b][k] from partials ----
    float sa[4], mx = -1e30f;
    #pragma unroll
    for (int k = 0; k < 4; ++k) {
        float s = attb[0];
        #pragma unroll
        for (int c = 0; c < 8; ++c) s += part[(b * 4 + k) * 8 + c];
        sa[k] = s;
        mx = fmaxf(mx, s);
    }
    float den = 0.f;
    #pragma unroll
    for (int k = 0; k < 4; ++k) { sa[k] = __expf(sa[k] - mx); den += sa[k]; }
    float inv = 1.f / den;
    #pragma unroll
    for (int k = 0; k < 4; ++k) sa[k] *= inv;

    // ---- phase B: att + newh copy + stores (jj pairs d and d+64) ----
    #pragma unroll
    for (int jj = 0; jj < 4; ++jj) {
        int hcol = jj * 16 + l15;                 // h in [0,64)
        #pragma unroll
        for (int r = 0; r < 4; ++r) {
            int n = n0 + wave * 16 + quad * 4 + r;
            float attRe = 0.f, attIm = 0.f;
            #pragma unroll
            for (int k = 0; k < 4; ++k) {
                const float* hb = hs + (((size_t)(b * 4 + k) * 1024 + n) * 128);
                float re = hb[hcol], im = hb[64 + hcol];
                float s, c;
                __sincosf(R[(size_t)k * 65536 + n * 64 + hcol] * PHASE_SCALE, &s, &c);
                attRe += sa[k] * (c * re - s * im);
                attIm += sa[k] * (s * re + c * im);
                if (k >= 1) {
                    size_t nb = (size_t)b * 524288 + (size_t)(k - 1) * 131072 + (size_t)n * 128;
                    newh[nb + hcol] = re;
                    newh[nb + 64 + hcol] = im;
                }
            }
            size_t ob = (size_t)(m0 + wave * 16 + quad * 4 + r) * 128;
            float oRe = acc[jj][r]     + bvec[(size_t)n * 128 + hcol]      + attRe;
            float oIm = acc[jj + 4][r] + bvec[(size_t)n * 128 + 64 + hcol] + attIm;
            out[ob + hcol] = oRe;
            out[ob + 64 + hcol] = oIm;
            size_t nb3 = (size_t)b * 524288 + 393216 + (size_t)n * 128;
            newh[nb3 + hcol] = oRe;
            newh[nb3 + 64 + hcol] = oIm;
        }
    }
}

extern "C" void kernel_launch(void* const* d_in, const int* in_sizes, int n_in,
                              void* d_out, int out_size, void* d_ws, size_t ws_size,
                              hipStream_t stream) {
    const float* inp  = (const float*)d_in[0];
    const float* sup  = (const float*)d_in[1];
    const float* hs   = (const float*)d_in[2];
    const float* W    = (const float*)d_in[3];
    const float* bvec = (const float*)d_in[4];
    const float* R    = (const float*)d_in[5];
    const float* gcw  = (const float*)d_in[6];
    const float* gcb  = (const float*)d_in[7];
    // d_in[8], d_in[9] (ev_att_w/b) dead: softmax over size-1 axis == 1
    const float* attw = (const float*)d_in[10];
    const float* attb = (const float*)d_in[11];

    float* out  = (float*)d_out;                    // (16,1024,128)
    float* newh = out + 2097152;                    // (16,4,1024,128)
    bf16*  Sbf  = (bf16*)newh;                      // S bf16 here until final_kernel

    char* w = (char*)d_ws;
    bf16*  xT0   = (bf16*)(w);                      // 8 MB  [16][256][1024]
    bf16*  xT1   = (bf16*)(w + 8388608);            // 8 MB
    bf16*  xT2   = (bf16*)(w + 16777216);           // 8 MB
    bf16*  xRow  = (bf16*)(w + 25165824);           // 8 MB  [16384][256]
    float* gcoF  = (float*)(w + 33554432);          // 8 MB  [16384][128]
    bf16*  gtAll = (bf16*)(w + 41943040);           // 256 KB [4][128][256]
    bf16*  WT    = (bf16*)(w + 42205184);           // 32 KB  [128][128]
    float* part  = (float*)(w + 42237952);          // 2 KB
    // total ~40.3 MB

    prep_kernel<<<10304, 256, 0, stream>>>((const float4*)sup, Sbf, R, gcw, W,
                                           gtAll, WT, inp, hs, xRow, xT0, attw, part);

    // hop1: x1 = S@x0 ; gcoF = x0@g0 + x1@g1
    cheb_mfma_kernel<<<256, 512, 0, stream>>>(Sbf, xT0, nullptr, xT1,
                                              xRow, gtAll + 32768, gtAll, gcoF, 1.0f, 0);
    // hop2: x2 = 2S@x1 - x0 ; gcoF += x2@g2
    cheb_mfma_kernel<<<256, 512, 0, stream>>>(Sbf, xT1, xT0, xT2,
                                              nullptr, gtAll + 2 * 32768, nullptr, gcoF, 2.0f, 1);
    // hop3: x3 = 2S@x2 - x1 ; gcoF += x3@g3 (no xT output)
    cheb_mfma_kernel<<<256, 512, 0, stream>>>(Sbf, xT2, xT1, nullptr,
                                              nullptr, gtAll + 3 * 32768, nullptr, gcoF, 2.0f, 1);

    // Sbf (in newh region) dead now -> final writes out + all of newh
    final_kernel<<<256, 256, 0, stream>>>(gcoF, gcb, WT, bvec, hs, R, part, attb, out, newh);
}